// Round 3
// baseline (371.621 us; speedup 1.0000x reference)
//
#include <hip/hip_runtime.h>
#include <hip/hip_bf16.h>
#include <math.h>

// Problem: B=8, NQ=1024, NKV=2048, D=1024, H=16, HD=64, inner=1024.
// f32 storage in/out; bf16 MFMA compute with fp32 accumulation.
//
// ws layout (ushort elems):
//   wqT 1M | wkT 1M | wvT 1M | woT 1M | latB 8M | datB 16M | Q 8M | K 16M
//   | Vt 16M = 68M elems = 136 MB.  AO aliases latB (dead after proj_qkv).

using short8  = __attribute__((ext_vector_type(8))) short;
using f32x4   = __attribute__((ext_vector_type(4))) float;
using uint4v  = __attribute__((ext_vector_type(4))) unsigned int;

__device__ __forceinline__ ushort f2bf(float f) {
    unsigned u = __builtin_bit_cast(unsigned, f);
    u = (u + 0x7FFFu + ((u >> 16) & 1u)) >> 16;
    return (ushort)u;
}
// pack two f32 -> two bf16 (round-half-up) in one dword: lo | hi<<16
__device__ __forceinline__ unsigned pack_bf2(float lo, float hi) {
    unsigned ulo = __builtin_bit_cast(unsigned, lo) + 0x8000u;
    unsigned uhi = __builtin_bit_cast(unsigned, hi) + 0x8000u;
    return __builtin_amdgcn_perm(uhi, ulo, 0x07060302);
}

// async global->LDS, 16B/lane. LDS dest = wave-uniform base + lane*16;
// global address is per-lane (swizzle the SOURCE address, never the dest).
__device__ __forceinline__ void gld_lds16(const ushort* g, ushort* l) {
    __builtin_amdgcn_global_load_lds(
        (const __attribute__((address_space(1))) unsigned int*)(const void*)g,
        (__attribute__((address_space(3))) unsigned int*)(void*)l,
        16, 0, 0);
}

// ---------------------------------------------------------------------------
// Fused prep (one launch instead of three):
//   blocks [0, 4096)      : latent f32 -> bf16       (8M elems)
//   blocks [4096, 12288)  : data   f32 -> bf16       (16M elems)
//   blocks [12288, 16384) : weight transpose+cvt, 4 matrices x 1024 tiles
// All branches are block-uniform; 256 threads everywhere.
// ---------------------------------------------------------------------------
__global__ void prep_fused(const float* __restrict__ latent, const float* __restrict__ data,
                           const float* __restrict__ wq, const float* __restrict__ wk,
                           const float* __restrict__ wv, const float* __restrict__ wo,
                           ushort* __restrict__ latB, ushort* __restrict__ datB,
                           ushort* __restrict__ wqT, ushort* __restrict__ wkT,
                           ushort* __restrict__ wvT, ushort* __restrict__ woT) {
    __shared__ ushort tile[32][33];
    const int bx  = blockIdx.x;
    const int tid = threadIdx.x;
    if (bx < 12288) {
        const float* in = (bx < 4096) ? latent : data;
        ushort* out     = (bx < 4096) ? latB : datB;
        int idx = (bx < 4096) ? bx : bx - 4096;
        int i = (idx * 256 + tid) * 8;
        float4 a = *(const float4*)(in + i);
        float4 b = *(const float4*)(in + i + 4);
        short8 o;
        o[0] = (short)f2bf(a.x); o[1] = (short)f2bf(a.y);
        o[2] = (short)f2bf(a.z); o[3] = (short)f2bf(a.w);
        o[4] = (short)f2bf(b.x); o[5] = (short)f2bf(b.y);
        o[6] = (short)f2bf(b.z); o[7] = (short)f2bf(b.w);
        *(short8*)(out + i) = o;
        return;
    }
    int rem = bx - 12288;
    int z   = rem >> 10;             // matrix 0..3
    int bxx = rem & 31;              // x-tile
    int byy = (rem >> 5) & 31;       // y-tile
    const float* in = (z == 0) ? wq : (z == 1) ? wk : (z == 2) ? wv : wo;
    ushort* out     = (z == 0) ? wqT : (z == 1) ? wkT : (z == 2) ? wvT : woT;
    int tx = tid & 31, ty = tid >> 5;    // 32 x 8
    int x = bxx * 32 + tx;
    int y = byy * 32;
#pragma unroll
    for (int i = 0; i < 32; i += 8)
        tile[ty + i][tx] = f2bf(in[(size_t)(y + ty + i) * 1024 + x]);
    __syncthreads();
    int x2 = byy * 32 + tx;
    int y2 = bxx * 32;
#pragma unroll
    for (int i = 0; i < 32; i += 8)
        out[(size_t)(y2 + ty + i) * 1024 + x2] = tile[tx][ty + i];
}

// ---------------------------------------------------------------------------
// 256x256 8-phase GEMM (T2+T3+T4+T5 stack), K=1024, ld=1024 for A and Bt.
// Used ONLY by proj_qkv (747-770 TF measured; m248 regime ceiling 848).
// R2 post-mortem: T1 swizzle cut FETCH 195->72 MB (mechanism confirmed) but
// time barely moved -> schedule-bound, not BW-bound. Keep swizzle, stop here.
// ---------------------------------------------------------------------------
template <int S>  // S = 64 for A halves, 32 for B halves
__device__ __forceinline__ void stage_half(const ushort* __restrict__ G, int rbase,
                                           ushort* tile, int H, int kcol,
                                           int wave, int lane) {
#pragma unroll
    for (int c = 0; c < 2; ++c) {
        int rho = c * 64 + wave * 8;                      // local row, 8-row group
        int gr0 = (rho / S) * (2 * S) + H * S + (rho % S); // global row in 256-tile
        int rig = lane >> 3;                               // row within group
        int q   = (lane & 7) ^ rig;                        // pre-swizzled src chunk
        gld_lds16(G + (size_t)(rbase + gr0 + rig) * 1024 + kcol + q * 8,
                  tile + gr0 * 64);
    }
}

__device__ __forceinline__ void gemm256_body(
        const ushort* __restrict__ A, const ushort* __restrict__ Bt,
        const float* __restrict__ bias, void* __restrict__ Cv,
        float scale, int mode, int bm, int bn) {
    __shared__ __align__(16) ushort sm[65536];   // 128 KiB
    ushort* As0 = sm;
    ushort* Bs0 = sm + 16384;
    ushort* As1 = sm + 32768;
    ushort* Bs1 = sm + 49152;

    const int tid  = threadIdx.x;
    const int wave = tid >> 6, lane = tid & 63;
    const int l15 = lane & 15, quad = lane >> 4;
    const int wm = wave >> 2, wn = wave & 3;
    const int m0 = bm * 256, n0 = bn * 256;

    const int rA  = wm * 128 + l15;          // frag row base in A-tile
    const int rB  = wn * 64 + l15;           // frag row base in B-tile
    const int cq0 = quad ^ (l15 & 7);        // swizzled chunk, kk=0
    const int cq1 = (4 + quad) ^ (l15 & 7);  // swizzled chunk, kk=1

    // --- prologue: tile0 all 4 halves, then tile1 {A-H0, B-H1, A-H1}.
    // vmcnt(6) completes the oldest 8 loads = all of tile0.
    stage_half<64>(A,  m0, As0, 0, 0,  wave, lane);
    stage_half<32>(Bt, n0, Bs0, 0, 0,  wave, lane);
    stage_half<32>(Bt, n0, Bs0, 1, 0,  wave, lane);
    stage_half<64>(A,  m0, As0, 1, 0,  wave, lane);
    stage_half<64>(A,  m0, As1, 0, 64, wave, lane);
    stage_half<32>(Bt, n0, Bs1, 1, 64, wave, lane);
    stage_half<64>(A,  m0, As1, 1, 64, wave, lane);
    asm volatile("s_waitcnt vmcnt(6)" ::: "memory");
    __builtin_amdgcn_s_barrier();

    f32x4 acc[8][4] = {};

#define LDA(MH)                                                                   \
    _Pragma("unroll")                                                             \
    for (int mi = 0; mi < 4; ++mi) {                                              \
        a[mi][0] = *(const short8*)(Ac + (rA + (MH) * 64 + mi * 16) * 64 + cq0 * 8); \
        a[mi][1] = *(const short8*)(Ac + (rA + (MH) * 64 + mi * 16) * 64 + cq1 * 8); \
    }
#define LDB(NH)                                                                   \
    _Pragma("unroll")                                                             \
    for (int ni = 0; ni < 2; ++ni) {                                              \
        b[ni][0] = *(const short8*)(Bc + (rB + (NH) * 32 + ni * 16) * 64 + cq0 * 8); \
        b[ni][1] = *(const short8*)(Bc + (rB + (NH) * 32 + ni * 16) * 64 + cq1 * 8); \
    }
#define MFMA_PHASE(MB, NB)                                                        \
    __builtin_amdgcn_s_barrier();                                                 \
    asm volatile("s_waitcnt lgkmcnt(0)" ::: "memory");                            \
    __builtin_amdgcn_sched_barrier(0);                                            \
    __builtin_amdgcn_s_setprio(1);                                                \
    _Pragma("unroll")                                                             \
    for (int mi = 0; mi < 4; ++mi)                                                \
        _Pragma("unroll")                                                         \
        for (int ni = 0; ni < 2; ++ni)                                            \
            _Pragma("unroll")                                                     \
            for (int kk = 0; kk < 2; ++kk)                                        \
                acc[(MB) * 4 + mi][(NB) * 2 + ni] =                               \
                    __builtin_amdgcn_mfma_f32_16x16x32_bf16(                      \
                        a[mi][kk], b[ni][kk], acc[(MB) * 4 + mi][(NB) * 2 + ni],  \
                        0, 0, 0);                                                 \
    __builtin_amdgcn_s_setprio(0);                                                \
    __builtin_amdgcn_s_barrier();

#pragma unroll 2
    for (int g = 0; g < 16; ++g) {
        ushort* Ac = (g & 1) ? As1 : As0;
        ushort* Bc = (g & 1) ? Bs1 : Bs0;
        ushort* Bn = (g & 1) ? Bs0 : Bs1;
        const int k1 = ((g + 1) & 15) * 64;   // wrap: tail stages harmless
        const int k2 = ((g + 2) & 15) * 64;
        short8 a[4][2], b[2][2];

        // ---- phase 1: Q(m0,n0); stage next-tile B-H0 into other buf
        LDA(0) LDB(0)
        stage_half<32>(Bt, n0, Bn, 0, k1, wave, lane);
        MFMA_PHASE(0, 0)

        // ---- phase 2: Q(m0,n1); A-H0 of this buf now free -> stage tile g+2
        LDB(1)
        stage_half<64>(A, m0, Ac, 0, k2, wave, lane);
        MFMA_PHASE(0, 1)

        // ---- phase 3: Q(m1,n1); B-H1 free -> stage tile g+2
        LDA(1)
        stage_half<32>(Bt, n0, Bc, 1, k2, wave, lane);
        MFMA_PHASE(1, 1)

        // ---- phase 4: Q(m1,n0); A-H1 free -> stage; counted drain (never 0)
        LDB(0)
        stage_half<64>(A, m0, Ac, 1, k2, wave, lane);
        asm volatile("s_waitcnt vmcnt(6)" ::: "memory");
        MFMA_PHASE(1, 0)
    }
#undef LDA
#undef LDB
#undef MFMA_PHASE

    // drain remaining in-flight stages before LDS goes out of scope
    asm volatile("s_waitcnt vmcnt(0)" ::: "memory");

    // --- epilogue
    float bvv[4];
    int   cols[4];
#pragma unroll
    for (int n4 = 0; n4 < 4; ++n4) {
        cols[n4] = n0 + wn * 64 + n4 * 16 + l15;
        bvv[n4]  = bias[cols[n4]];
    }
#pragma unroll
    for (int m8 = 0; m8 < 8; ++m8) {
        int rbase = m0 + wm * 128 + m8 * 16 + quad * 4;
#pragma unroll
        for (int n4 = 0; n4 < 4; ++n4) {
            float v[4];
#pragma unroll
            for (int rr = 0; rr < 4; ++rr)
                v[rr] = (acc[m8][n4][rr] + bvv[n4]) * scale;
            if (mode == 1) {
                // 4 consecutive kv -> one 8B store at pi-permuted position
                int kvl = rbase & 2047;
                int pos = (kvl & ~31) + ((kvl >> 2) & 3) * 8 + ((kvl >> 4) & 1) * 4;
                size_t base = ((size_t)((rbase >> 11) * 1024 + cols[n4])) * 2048 + pos;
                uint2 o;
                o.x = pack_bf2(v[0], v[1]);
                o.y = pack_bf2(v[2], v[3]);
                *(uint2*)((ushort*)Cv + base) = o;
            } else if (mode == 0) {
#pragma unroll
                for (int rr = 0; rr < 4; ++rr)
                    ((ushort*)Cv)[(size_t)(rbase + rr) * 1024 + cols[n4]] = f2bf(v[rr]);
            } else {
#pragma unroll
                for (int rr = 0; rr < 4; ++rr)
                    ((float*)Cv)[(size_t)(rbase + rr) * 1024 + cols[n4]] = v[rr];
            }
        }
    }
}

// Fused Q/K/V projections: one launch, 640 blocks (Q:128, K:256, V:256).
// T1 bijective chunked XCD swizzle (640 % 8 == 0).
__global__ __launch_bounds__(512, 2) void proj_qkv(
        const ushort* __restrict__ latB, const ushort* __restrict__ datB,
        const ushort* __restrict__ wqT, const ushort* __restrict__ wkT,
        const ushort* __restrict__ wvT,
        const float* __restrict__ bq, const float* __restrict__ bk,
        const float* __restrict__ bv,
        ushort* __restrict__ Qb, ushort* __restrict__ Kb, ushort* __restrict__ Vtb,
        float qscale) {
    int bid = ((int)blockIdx.x & 7) * 80 + ((int)blockIdx.x >> 3);
    const ushort* A;
    const ushort* W;
    const float*  bias;
    void*         C;
    float sc;
    int mode, idx;
    if (bid < 128)      { A = latB; W = wqT; bias = bq; C = Qb;  sc = qscale; mode = 0; idx = bid; }
    else if (bid < 384) { A = datB; W = wkT; bias = bk; C = Kb;  sc = 1.f;    mode = 0; idx = bid - 128; }
    else                { A = datB; W = wvT; bias = bv; C = Vtb; sc = 1.f;    mode = 1; idx = bid - 384; }
    gemm256_body(A, W, bias, C, sc, mode, idx >> 2, idx & 3);
}

// ---------------------------------------------------------------------------
// 128^2-tile GEMM (proven ~400-500 TF class at K=1024) — O projection only.
// Grid: (Mtiles, 8) — m on x so the 8 blocks sharing an A-strip are spaced
// Mtiles apart in dispatch order -> same XCD L2.
// ---------------------------------------------------------------------------
template <int MODE>
__global__ void gemm_bt(const ushort* __restrict__ A, const ushort* __restrict__ Bt,
                        const float* __restrict__ bias, void* __restrict__ Cv,
                        int K, float scale) {
    __shared__ __align__(16) ushort As[128 * 32];
    __shared__ __align__(16) ushort Bs[128 * 32];
    const int tid  = threadIdx.x;
    const int wave = tid >> 6, lane = tid & 63;
    const int l15 = lane & 15, quad = lane >> 4;
    const int wm = wave & 1, wn = wave >> 1;
    const int m0 = blockIdx.x * 128;
    const int n0 = blockIdx.y * 128;

    f32x4 acc[4][4] = {};

    for (int k0 = 0; k0 < K; k0 += 32) {
        __syncthreads();
#pragma unroll
        for (int i = 0; i < 2; ++i) {
            int f   = (i * 256 + tid) * 8;
            int row = f >> 5, col = f & 31;
            gld_lds16(A  + (size_t)(m0 + row) * K + k0 + col, As + (i * 256 + wave * 64) * 8);
            gld_lds16(Bt + (size_t)(n0 + row) * K + k0 + col, Bs + (i * 256 + wave * 64) * 8);
        }
        __syncthreads();

        short8 a[4], b[4];
#pragma unroll
        for (int mi = 0; mi < 4; ++mi)
            a[mi] = *(const short8*)(As + (wm * 64 + mi * 16 + l15) * 32 + quad * 8);
#pragma unroll
        for (int ni = 0; ni < 4; ++ni)
            b[ni] = *(const short8*)(Bs + (wn * 64 + ni * 16 + l15) * 32 + quad * 8);
#pragma unroll
        for (int mi = 0; mi < 4; ++mi)
#pragma unroll
            for (int ni = 0; ni < 4; ++ni)
                acc[mi][ni] = __builtin_amdgcn_mfma_f32_16x16x32_bf16(a[mi], b[ni], acc[mi][ni], 0, 0, 0);
    }

    float bv[4];
    int   cols[4];
#pragma unroll
    for (int ni = 0; ni < 4; ++ni) {
        cols[ni] = n0 + wn * 64 + ni * 16 + l15;
        bv[ni]   = bias[cols[ni]];
    }
#pragma unroll
    for (int mi = 0; mi < 4; ++mi) {
        int rbase = m0 + wm * 64 + mi * 16 + quad * 4;
#pragma unroll
        for (int ni = 0; ni < 4; ++ni) {
            float v[4];
#pragma unroll
            for (int rr = 0; rr < 4; ++rr)
                v[rr] = (acc[mi][ni][rr] + bv[ni]) * scale;
            if (MODE == 1) {
                int kvl = rbase & 2047;
                int pos = (kvl & ~31) + ((kvl >> 2) & 3) * 8 + ((kvl >> 4) & 1) * 4;
                size_t base = ((size_t)((rbase >> 11) * 1024 + cols[ni])) * 2048 + pos;
                uint2 o;
                o.x = pack_bf2(v[0], v[1]);
                o.y = pack_bf2(v[2], v[3]);
                *(uint2*)((ushort*)Cv + base) = o;
            } else {
#pragma unroll
                for (int rr = 0; rr < 4; ++rr) {
                    int row = rbase + rr;
                    if (MODE == 0)
                        ((ushort*)Cv)[(size_t)row * 1024 + cols[ni]] = f2bf(v[rr]);
                    else
                        ((float*)Cv)[(size_t)row * 1024 + cols[ni]] = v[rr];
                }
            }
        }
    }
}

// ---------------------------------------------------------------------------
// Fused flash attention, S^T formulation, fixed-max base-2 softmax.
// R3: T14 async-STAGE split (m214 v27, +17% there). Staging converted from
// global_load_lds (whose vmcnt is force-drained at every __syncthreads) to
// reg-staged: loads for tile t+1 issued AFTER barrier (B) -> no barrier
// between issue and use -> HBM/L2 latency hides under tile t's compute.
// ds_write waits on the loads via register dependency only. Same per-lane
// source addresses + same linear LDS dests as the gld_lds version -> LDS
// contents bit-identical; compute unchanged. +32 staging VGPRs ->
// launch_bounds (256,3) to stay spill-free (occupancy 4->3 blocks/CU).
// ---------------------------------------------------------------------------
__global__ __launch_bounds__(256, 3) void attn_fused(const ushort* __restrict__ Q,
                                                     const ushort* __restrict__ K,
                                                     const ushort* __restrict__ Vt,
                                                     ushort* __restrict__ O) {
    __shared__ __align__(16) ushort smem[2 * 8192];
    ushort* Ks  = smem;
    ushort* Vts = smem + 8192;

    const int tid  = threadIdx.x;
    const int wave = tid >> 6, lane = tid & 63;
    const int l15 = lane & 15, quad = lane >> 4;
    const int bx = blockIdx.x;
    // q-tile in HIGH bits: the 8 q-blocks of one (b,h) are == mod 8 in
    // dispatch order -> same XCD -> K/V tiles shared in that L2.
    const int bh = bx & 127, h = bh & 15, b = bh >> 4;
    const int q0 = (bx >> 7) * 128;

    const ushort* Qg = Q + ((size_t)(b * 1024 + q0)) * 1024 + h * 64;
    const ushort* Kg = K + ((size_t)(b * 2048)) * 1024 + h * 64;
    const ushort* Vg = Vt + ((size_t)(b * 1024 + h * 64)) * 2048;

    // --- Q fragments straight to registers (B-frag: n=q=l15, k=quad*8+j)
    short8 bq[2][2];
#pragma unroll
    for (int qt = 0; qt < 2; ++qt) {
        int row = wave * 32 + qt * 16 + l15;
#pragma unroll
        for (int ks = 0; ks < 2; ++ks)
            bq[ks][qt] = *(const short8*)(Qg + (size_t)row * 1024 + ks * 32 + quad * 8);
    }

    f32x4 Oacc[4][2] = {};
    float l_run[2] = {0.f, 0.f};

    const int rig = lane >> 3;        // K staging: row in 8-row group
    const int scb8 = (lane & 7) ^ rig;
    const int riv = lane >> 4;        // V staging: row in 4-row group
    const int cb16 = lane & 15;

    // --- staging registers + prologue load of tile 0
    short8 kreg[4], vreg[4];
#pragma unroll
    for (int g = 0; g < 4; ++g) {
        int G = wave * 4 + g;
        kreg[g] = *(const short8*)(Kg + (size_t)(G * 8 + rig) * 1024 + scb8 * 8);
        int vrow = G * 4 + riv;
        int scv = cb16 ^ (vrow & 15);
        vreg[g] = *(const short8*)(Vg + (size_t)vrow * 2048 + scv * 8);
    }

    for (int kv0 = 0; kv0 < 2048; kv0 += 128) {
        __syncthreads();   // (A) previous iter's LDS reads complete
        // --- ds_write tile t from regs (reg dependency waits on the loads;
        // dests identical to the old gld_lds layout: base + lane*16B)
#pragma unroll
        for (int g = 0; g < 4; ++g) {
            int G = wave * 4 + g;
            *(short8*)(Ks  + G * 512 + lane * 8) = kreg[g];
            *(short8*)(Vts + G * 512 + lane * 8) = vreg[g];
        }
        __syncthreads();   // (B) writes visible; no vmem outstanding here

        // --- issue prefetch for tile t+1 (latency hides under compute below)
        if (kv0 + 128 < 2048) {
            int kvn = kv0 + 128;
#pragma unroll
            for (int g = 0; g < 4; ++g) {
                int G = wave * 4 + g;
                kreg[g] = *(const short8*)(Kg + (size_t)(kvn + G * 8 + rig) * 1024 + scb8 * 8);
                int vrow = G * 4 + riv;
                int scv = cb16 ^ (vrow & 15);
                vreg[g] = *(const short8*)(Vg + (size_t)vrow * 2048 + kvn + scv * 8);
            }
        }

        // --- per kv-tile: S^T tile = K·Q^T, then exp2 + sum + pack at once
        unsigned pk[8][2][2];
#pragma unroll
        for (int kvt = 0; kvt < 8; ++kvt) {
            f32x4 s0 = {}, s1 = {};
#pragma unroll
            for (int ks = 0; ks < 2; ++ks) {
                int ck = ((ks * 4 + quad) ^ (l15 & 7)) * 8;   // swizzled chunk
                short8 ak = *(const short8*)(Ks + (kvt * 16 + l15) * 64 + ck);
                s0 = __builtin_amdgcn_mfma_f32_16x16x32_bf16(ak, bq[ks][0], s0, 0, 0, 0);
                s1 = __builtin_amdgcn_mfma_f32_16x16x32_bf16(ak, bq[ks][1], s1, 0, 0, 0);
            }
            float p0[4], p1[4];
#pragma unroll
            for (int rr = 0; rr < 4; ++rr) {
                p0[rr] = __builtin_amdgcn_exp2f(s0[rr]);
                p1[rr] = __builtin_amdgcn_exp2f(s1[rr]);
                l_run[0] += p0[rr];
                l_run[1] += p1[rr];
            }
            pk[kvt][0][0] = pack_bf2(p0[0], p0[1]);
            pk[kvt][0][1] = pack_bf2(p0[2], p0[3]);
            pk[kvt][1][0] = pack_bf2(p1[0], p1[1]);
            pk[kvt][1][1] = pack_bf2(p1[2], p1[3]);
        }

        // --- O^T += V^T · P^T : P^T B-frags straight from pk registers
#pragma unroll
        for (int sp = 0; sp < 4; ++sp) {
#pragma unroll
            for (int dt = 0; dt < 4; ++dt) {
                int cv = ((sp * 4 + quad) ^ l15) * 8;
                short8 av = *(const short8*)(Vts + (dt * 16 + l15) * 128 + cv);
#pragma unroll
                for (int qt = 0; qt < 2; ++qt) {
                    uint4v u = {pk[2 * sp][qt][0], pk[2 * sp][qt][1],
                                pk[2 * sp + 1][qt][0], pk[2 * sp + 1][qt][1]};
                    short8 bp = __builtin_bit_cast(short8, u);
                    Oacc[dt][qt] = __builtin_amdgcn_mfma_f32_16x16x32_bf16(av, bp, Oacc[dt][qt], 0, 0, 0);
                }
            }
        }
    }

    // --- epilogue: reduce l across quads, O = (O^T)^T / l, packed 8B stores
#pragma unroll
    for (int qt = 0; qt < 2; ++qt) {
        float l = l_run[qt];
        l += __shfl_xor(l, 16);
        l += __shfl_xor(l, 32);
        float inv = 1.f / l;
        int qg = q0 + wave * 32 + qt * 16 + l15;
#pragma unroll
        for (int dt = 0; dt < 4; ++dt) {
            uint2 o;
            o.x = pack_bf2(Oacc[dt][qt][0] * inv, Oacc[dt][qt][1] * inv);
            o.y = pack_bf2(Oacc[dt][qt][2] * inv, Oacc[dt][qt][3] * inv);
            *(uint2*)(O + ((size_t)(b * 1024 + qg)) * 1024 + h * 64 + dt * 16 + quad * 4) = o;
        }
    }
}

// ---------------------------------------------------------------------------
extern "C" void kernel_launch(void* const* d_in, const int* in_sizes, int n_in,
                              void* d_out, int out_size, void* d_ws, size_t ws_size,
                              hipStream_t stream) {
    const float* latent = (const float*)d_in[0];
    const float* data   = (const float*)d_in[1];
    const float* wq     = (const float*)d_in[2];
    const float* bq     = (const float*)d_in[3];
    const float* wk     = (const float*)d_in[4];
    const float* bk     = (const float*)d_in[5];
    const float* wv     = (const float*)d_in[6];
    const float* bv     = (const float*)d_in[7];
    const float* wo     = (const float*)d_in[8];
    const float* bo     = (const float*)d_in[9];
    float* out = (float*)d_out;

    ushort* ws   = (ushort*)d_ws;
    ushort* wqT  = ws;
    ushort* wkT  = wqT + (1u << 20);
    ushort* wvT  = wkT + (1u << 20);
    ushort* woT  = wvT + (1u << 20);
    ushort* latB = woT + (1u << 20);
    ushort* datB = latB + (8u << 20);
    ushort* Qb   = datB + (16u << 20);
    ushort* Kb   = Qb + (8u << 20);
    ushort* Vtb  = Kb + (16u << 20);
    ushort* AO   = latB;               // alias: latB dead after proj_qkv
    // total ws footprint: 68M ushorts = 136 MB

    // fused prep: latent/data cvt + 4 weight transposes, one launch
    prep_fused<<<dim3(16384), 256, 0, stream>>>(latent, data, wq, wk, wv, wo,
                                                latB, datB, wqT, wkT, wvT, woT);

    const float qscale = 0.125f * 1.44269504088896340736f;  // HD^-0.5 * log2(e)
    // Q | K | V projections in one 640-block launch (256^2 8-phase GEMM + T1)
    proj_qkv<<<dim3(640), 512, 0, stream>>>(latB, datB, wqT, wkT, wvT,
                                            bq, bk, bv, Qb, Kb, Vtb, qscale);
    // fused attention -> AO [8192 x 1024] bf16
    attn_fused<<<dim3(1024), 256, 0, stream>>>(Qb, Kb, Vtb, AO);
    // out = AO @ wo + bo                             [8192 x 1024] f32
    gemm_bt<2><<<dim3(64, 8), 256, 0, stream>>>(AO, woT, bo, out, 1024, 1.0f);
}

// Round 4
// 364.494 us; speedup vs baseline: 1.0196x; 1.0196x over previous
//
#include <hip/hip_runtime.h>
#include <hip/hip_bf16.h>
#include <math.h>

// Problem: B=8, NQ=1024, NKV=2048, D=1024, H=16, HD=64, inner=1024.
// f32 storage in/out; bf16 MFMA compute with fp32 accumulation.
//
// ws layout (ushort elems):
//   wqT 1M | wkT 1M | wvT 1M | woT 1M | latB 8M | datB 16M | Q 8M | K 16M
//   | Vt 16M = 68M elems = 136 MB.  AO aliases latB (dead after proj_qkv).

using short8  = __attribute__((ext_vector_type(8))) short;
using f32x4   = __attribute__((ext_vector_type(4))) float;
using uint4v  = __attribute__((ext_vector_type(4))) unsigned int;

__device__ __forceinline__ ushort f2bf(float f) {
    unsigned u = __builtin_bit_cast(unsigned, f);
    u = (u + 0x7FFFu + ((u >> 16) & 1u)) >> 16;
    return (ushort)u;
}
// pack two f32 -> two bf16 (round-half-up) in one dword: lo | hi<<16
__device__ __forceinline__ unsigned pack_bf2(float lo, float hi) {
    unsigned ulo = __builtin_bit_cast(unsigned, lo) + 0x8000u;
    unsigned uhi = __builtin_bit_cast(unsigned, hi) + 0x8000u;
    return __builtin_amdgcn_perm(uhi, ulo, 0x07060302);
}

// async global->LDS, 16B/lane. LDS dest = wave-uniform base + lane*16;
// global address is per-lane (swizzle the SOURCE address, never the dest).
__device__ __forceinline__ void gld_lds16(const ushort* g, ushort* l) {
    __builtin_amdgcn_global_load_lds(
        (const __attribute__((address_space(1))) unsigned int*)(const void*)g,
        (__attribute__((address_space(3))) unsigned int*)(void*)l,
        16, 0, 0);
}

// ---------------------------------------------------------------------------
// Fused prep (one launch instead of three):
//   blocks [0, 4096)      : latent f32 -> bf16       (8M elems)
//   blocks [4096, 12288)  : data   f32 -> bf16       (16M elems)
//   blocks [12288, 16384) : weight transpose+cvt, 4 matrices x 1024 tiles
// ---------------------------------------------------------------------------
__global__ void prep_fused(const float* __restrict__ latent, const float* __restrict__ data,
                           const float* __restrict__ wq, const float* __restrict__ wk,
                           const float* __restrict__ wv, const float* __restrict__ wo,
                           ushort* __restrict__ latB, ushort* __restrict__ datB,
                           ushort* __restrict__ wqT, ushort* __restrict__ wkT,
                           ushort* __restrict__ wvT, ushort* __restrict__ woT) {
    __shared__ ushort tile[32][33];
    const int bx  = blockIdx.x;
    const int tid = threadIdx.x;
    if (bx < 12288) {
        const float* in = (bx < 4096) ? latent : data;
        ushort* out     = (bx < 4096) ? latB : datB;
        int idx = (bx < 4096) ? bx : bx - 4096;
        int i = (idx * 256 + tid) * 8;
        float4 a = *(const float4*)(in + i);
        float4 b = *(const float4*)(in + i + 4);
        short8 o;
        o[0] = (short)f2bf(a.x); o[1] = (short)f2bf(a.y);
        o[2] = (short)f2bf(a.z); o[3] = (short)f2bf(a.w);
        o[4] = (short)f2bf(b.x); o[5] = (short)f2bf(b.y);
        o[6] = (short)f2bf(b.z); o[7] = (short)f2bf(b.w);
        *(short8*)(out + i) = o;
        return;
    }
    int rem = bx - 12288;
    int z   = rem >> 10;             // matrix 0..3
    int bxx = rem & 31;              // x-tile
    int byy = (rem >> 5) & 31;       // y-tile
    const float* in = (z == 0) ? wq : (z == 1) ? wk : (z == 2) ? wv : wo;
    ushort* out     = (z == 0) ? wqT : (z == 1) ? wkT : (z == 2) ? wvT : woT;
    int tx = tid & 31, ty = tid >> 5;    // 32 x 8
    int x = bxx * 32 + tx;
    int y = byy * 32;
#pragma unroll
    for (int i = 0; i < 32; i += 8)
        tile[ty + i][tx] = f2bf(in[(size_t)(y + ty + i) * 1024 + x]);
    __syncthreads();
    int x2 = byy * 32 + tx;
    int y2 = bxx * 32;
#pragma unroll
    for (int i = 0; i < 32; i += 8)
        out[(size_t)(y2 + ty + i) * 1024 + x2] = tile[tx][ty + i];
}

// ---------------------------------------------------------------------------
// 256x256 8-phase GEMM (T2+T3+T4+T5 stack), K=1024, ld=1024 for A and Bt.
// R4: all-B-in-regs (b[4][2], +16 VGPR) removes ph4's redundant LDB reload:
// ds_reads/K-step/wave 28 -> 24 (the distinct-fragment minimum). Safety
// unchanged: vmcnt(6) at iter g-1 ph4 completes ALL four halves of tile g,
// so ph1 may read both B halves.
// ---------------------------------------------------------------------------
template <int S>  // S = 64 for A halves, 32 for B halves
__device__ __forceinline__ void stage_half(const ushort* __restrict__ G, int rbase,
                                           ushort* tile, int H, int kcol,
                                           int wave, int lane) {
#pragma unroll
    for (int c = 0; c < 2; ++c) {
        int rho = c * 64 + wave * 8;                      // local row, 8-row group
        int gr0 = (rho / S) * (2 * S) + H * S + (rho % S); // global row in 256-tile
        int rig = lane >> 3;                               // row within group
        int q   = (lane & 7) ^ rig;                        // pre-swizzled src chunk
        gld_lds16(G + (size_t)(rbase + gr0 + rig) * 1024 + kcol + q * 8,
                  tile + gr0 * 64);
    }
}

__device__ __forceinline__ void gemm256_body(
        const ushort* __restrict__ A, const ushort* __restrict__ Bt,
        const float* __restrict__ bias, void* __restrict__ Cv,
        float scale, int mode, int bm, int bn) {
    __shared__ __align__(16) ushort sm[65536];   // 128 KiB
    ushort* As0 = sm;
    ushort* Bs0 = sm + 16384;
    ushort* As1 = sm + 32768;
    ushort* Bs1 = sm + 49152;

    const int tid  = threadIdx.x;
    const int wave = tid >> 6, lane = tid & 63;
    const int l15 = lane & 15, quad = lane >> 4;
    const int wm = wave >> 2, wn = wave & 3;
    const int m0 = bm * 256, n0 = bn * 256;

    const int rA  = wm * 128 + l15;          // frag row base in A-tile
    const int rB  = wn * 64 + l15;           // frag row base in B-tile
    const int cq0 = quad ^ (l15 & 7);        // swizzled chunk, kk=0
    const int cq1 = (4 + quad) ^ (l15 & 7);  // swizzled chunk, kk=1

    // --- prologue: tile0 all 4 halves, then tile1 {A-H0, B-H1, A-H1}.
    // vmcnt(6) completes the oldest 8 loads = all of tile0.
    stage_half<64>(A,  m0, As0, 0, 0,  wave, lane);
    stage_half<32>(Bt, n0, Bs0, 0, 0,  wave, lane);
    stage_half<32>(Bt, n0, Bs0, 1, 0,  wave, lane);
    stage_half<64>(A,  m0, As0, 1, 0,  wave, lane);
    stage_half<64>(A,  m0, As1, 0, 64, wave, lane);
    stage_half<32>(Bt, n0, Bs1, 1, 64, wave, lane);
    stage_half<64>(A,  m0, As1, 1, 64, wave, lane);
    asm volatile("s_waitcnt vmcnt(6)" ::: "memory");
    __builtin_amdgcn_s_barrier();

    f32x4 acc[8][4] = {};

#define LDA(MH)                                                                   \
    _Pragma("unroll")                                                             \
    for (int mi = 0; mi < 4; ++mi) {                                              \
        a[mi][0] = *(const short8*)(Ac + (rA + (MH) * 64 + mi * 16) * 64 + cq0 * 8); \
        a[mi][1] = *(const short8*)(Ac + (rA + (MH) * 64 + mi * 16) * 64 + cq1 * 8); \
    }
#define LDB_ALL                                                                   \
    _Pragma("unroll")                                                             \
    for (int nj = 0; nj < 4; ++nj) {                                              \
        b[nj][0] = *(const short8*)(Bc + (rB + nj * 16) * 64 + cq0 * 8);          \
        b[nj][1] = *(const short8*)(Bc + (rB + nj * 16) * 64 + cq1 * 8);          \
    }
#define MFMA_PHASE(MB, NB)                                                        \
    __builtin_amdgcn_s_barrier();                                                 \
    asm volatile("s_waitcnt lgkmcnt(0)" ::: "memory");                            \
    __builtin_amdgcn_sched_barrier(0);                                            \
    __builtin_amdgcn_s_setprio(1);                                                \
    _Pragma("unroll")                                                             \
    for (int mi = 0; mi < 4; ++mi)                                                \
        _Pragma("unroll")                                                         \
        for (int ni = 0; ni < 2; ++ni)                                            \
            _Pragma("unroll")                                                     \
            for (int kk = 0; kk < 2; ++kk)                                        \
                acc[(MB) * 4 + mi][(NB) * 2 + ni] =                               \
                    __builtin_amdgcn_mfma_f32_16x16x32_bf16(                      \
                        a[mi][kk], b[(NB) * 2 + ni][kk],                          \
                        acc[(MB) * 4 + mi][(NB) * 2 + ni], 0, 0, 0);              \
    __builtin_amdgcn_s_setprio(0);                                                \
    __builtin_amdgcn_s_barrier();

#pragma unroll 2
    for (int g = 0; g < 16; ++g) {
        ushort* Ac = (g & 1) ? As1 : As0;
        ushort* Bc = (g & 1) ? Bs1 : Bs0;
        ushort* Bn = (g & 1) ? Bs0 : Bs1;
        const int k1 = ((g + 1) & 15) * 64;   // wrap: tail stages harmless
        const int k2 = ((g + 2) & 15) * 64;
        short8 a[4][2], b[4][2];

        // ---- phase 1: Q(m0,n0); all B frags; stage next-tile B-H0
        LDA(0) LDB_ALL
        stage_half<32>(Bt, n0, Bn, 0, k1, wave, lane);
        MFMA_PHASE(0, 0)

        // ---- phase 2: Q(m0,n1); no ds_reads; stage tile g+2 A-H0
        stage_half<64>(A, m0, Ac, 0, k2, wave, lane);
        MFMA_PHASE(0, 1)

        // ---- phase 3: Q(m1,n1); A second half; stage tile g+2 B-H1
        LDA(1)
        stage_half<32>(Bt, n0, Bc, 1, k2, wave, lane);
        MFMA_PHASE(1, 1)

        // ---- phase 4: Q(m1,n0); no ds_reads; stage; counted drain (never 0)
        stage_half<64>(A, m0, Ac, 1, k2, wave, lane);
        asm volatile("s_waitcnt vmcnt(6)" ::: "memory");
        MFMA_PHASE(1, 0)
    }
#undef LDA
#undef LDB_ALL
#undef MFMA_PHASE

    // drain remaining in-flight stages before LDS goes out of scope
    asm volatile("s_waitcnt vmcnt(0)" ::: "memory");

    // --- epilogue
    float bvv[4];
    int   cols[4];
#pragma unroll
    for (int n4 = 0; n4 < 4; ++n4) {
        cols[n4] = n0 + wn * 64 + n4 * 16 + l15;
        bvv[n4]  = bias[cols[n4]];
    }
#pragma unroll
    for (int m8 = 0; m8 < 8; ++m8) {
        int rbase = m0 + wm * 128 + m8 * 16 + quad * 4;
#pragma unroll
        for (int n4 = 0; n4 < 4; ++n4) {
            float v[4];
#pragma unroll
            for (int rr = 0; rr < 4; ++rr)
                v[rr] = (acc[m8][n4][rr] + bvv[n4]) * scale;
            if (mode == 1) {
                // 4 consecutive kv -> one 8B store at pi-permuted position
                int kvl = rbase & 2047;
                int pos = (kvl & ~31) + ((kvl >> 2) & 3) * 8 + ((kvl >> 4) & 1) * 4;
                size_t base = ((size_t)((rbase >> 11) * 1024 + cols[n4])) * 2048 + pos;
                uint2 o;
                o.x = pack_bf2(v[0], v[1]);
                o.y = pack_bf2(v[2], v[3]);
                *(uint2*)((ushort*)Cv + base) = o;
            } else if (mode == 0) {
#pragma unroll
                for (int rr = 0; rr < 4; ++rr)
                    ((ushort*)Cv)[(size_t)(rbase + rr) * 1024 + cols[n4]] = f2bf(v[rr]);
            } else {
#pragma unroll
                for (int rr = 0; rr < 4; ++rr)
                    ((float*)Cv)[(size_t)(rbase + rr) * 1024 + cols[n4]] = v[rr];
            }
        }
    }
}

// Fused Q/K/V projections: one launch, 640 blocks (Q:128, K:256, V:256).
// T1 bijective chunked XCD swizzle (640 % 8 == 0).
__global__ __launch_bounds__(512, 2) void proj_qkv(
        const ushort* __restrict__ latB, const ushort* __restrict__ datB,
        const ushort* __restrict__ wqT, const ushort* __restrict__ wkT,
        const ushort* __restrict__ wvT,
        const float* __restrict__ bq, const float* __restrict__ bk,
        const float* __restrict__ bv,
        ushort* __restrict__ Qb, ushort* __restrict__ Kb, ushort* __restrict__ Vtb,
        float qscale) {
    int bid = ((int)blockIdx.x & 7) * 80 + ((int)blockIdx.x >> 3);
    const ushort* A;
    const ushort* W;
    const float*  bias;
    void*         C;
    float sc;
    int mode, idx;
    if (bid < 128)      { A = latB; W = wqT; bias = bq; C = Qb;  sc = qscale; mode = 0; idx = bid; }
    else if (bid < 384) { A = datB; W = wkT; bias = bk; C = Kb;  sc = 1.f;    mode = 0; idx = bid - 128; }
    else                { A = datB; W = wvT; bias = bv; C = Vtb; sc = 1.f;    mode = 1; idx = bid - 384; }
    gemm256_body(A, W, bias, C, sc, mode, idx >> 2, idx & 3);
}

// ---------------------------------------------------------------------------
// 128^2-tile GEMM (proven ~400-450 TF class at K=1024) — O projection only.
// Grid: (Mtiles, 8) — m on x so the 8 blocks sharing an A-strip are spaced
// Mtiles apart in dispatch order -> same XCD L2.
// ---------------------------------------------------------------------------
template <int MODE>
__global__ void gemm_bt(const ushort* __restrict__ A, const ushort* __restrict__ Bt,
                        const float* __restrict__ bias, void* __restrict__ Cv,
                        int K, float scale) {
    __shared__ __align__(16) ushort As[128 * 32];
    __shared__ __align__(16) ushort Bs[128 * 32];
    const int tid  = threadIdx.x;
    const int wave = tid >> 6, lane = tid & 63;
    const int l15 = lane & 15, quad = lane >> 4;
    const int wm = wave & 1, wn = wave >> 1;
    const int m0 = blockIdx.x * 128;
    const int n0 = blockIdx.y * 128;

    f32x4 acc[4][4] = {};

    for (int k0 = 0; k0 < K; k0 += 32) {
        __syncthreads();
#pragma unroll
        for (int i = 0; i < 2; ++i) {
            int f   = (i * 256 + tid) * 8;
            int row = f >> 5, col = f & 31;
            gld_lds16(A  + (size_t)(m0 + row) * K + k0 + col, As + (i * 256 + wave * 64) * 8);
            gld_lds16(Bt + (size_t)(n0 + row) * K + k0 + col, Bs + (i * 256 + wave * 64) * 8);
        }
        __syncthreads();

        short8 a[4], b[4];
#pragma unroll
        for (int mi = 0; mi < 4; ++mi)
            a[mi] = *(const short8*)(As + (wm * 64 + mi * 16 + l15) * 32 + quad * 8);
#pragma unroll
        for (int ni = 0; ni < 4; ++ni)
            b[ni] = *(const short8*)(Bs + (wn * 64 + ni * 16 + l15) * 32 + quad * 8);
#pragma unroll
        for (int mi = 0; mi < 4; ++mi)
#pragma unroll
            for (int ni = 0; ni < 4; ++ni)
                acc[mi][ni] = __builtin_amdgcn_mfma_f32_16x16x32_bf16(a[mi], b[ni], acc[mi][ni], 0, 0, 0);
    }

    float bv[4];
    int   cols[4];
#pragma unroll
    for (int ni = 0; ni < 4; ++ni) {
        cols[ni] = n0 + wn * 64 + ni * 16 + l15;
        bv[ni]   = bias[cols[ni]];
    }
#pragma unroll
    for (int mi = 0; mi < 4; ++mi) {
        int rbase = m0 + wm * 64 + mi * 16 + quad * 4;
#pragma unroll
        for (int ni = 0; ni < 4; ++ni) {
            float v[4];
#pragma unroll
            for (int rr = 0; rr < 4; ++rr)
                v[rr] = (acc[mi][ni][rr] + bv[ni]) * scale;
            if (MODE == 1) {
                int kvl = rbase & 2047;
                int pos = (kvl & ~31) + ((kvl >> 2) & 3) * 8 + ((kvl >> 4) & 1) * 4;
                size_t base = ((size_t)((rbase >> 11) * 1024 + cols[ni])) * 2048 + pos;
                uint2 o;
                o.x = pack_bf2(v[0], v[1]);
                o.y = pack_bf2(v[2], v[3]);
                *(uint2*)((ushort*)Cv + base) = o;
            } else {
#pragma unroll
                for (int rr = 0; rr < 4; ++rr) {
                    int row = rbase + rr;
                    if (MODE == 0)
                        ((ushort*)Cv)[(size_t)row * 1024 + cols[ni]] = f2bf(v[rr]);
                    else
                        ((float*)Cv)[(size_t)row * 1024 + cols[ni]] = v[rr];
                }
            }
        }
    }
}

// ---------------------------------------------------------------------------
// Fused flash attention, S^T formulation, fixed-max base-2 softmax.
// R4: reverted to the proven gld_lds staging (R3's T14 reg-staging was net
// negative: reg-staging cost > async gain when gld_lds works — catalog T14
// note) + T5 setprio: compute region at prio 1, stage+barriers at prio 0
// (m191: +4-7% on attn; blocks on a CU sit at different loop phases).
// ---------------------------------------------------------------------------
__global__ __launch_bounds__(256, 4) void attn_fused(const ushort* __restrict__ Q,
                                                     const ushort* __restrict__ K,
                                                     const ushort* __restrict__ Vt,
                                                     ushort* __restrict__ O) {
    __shared__ __align__(16) ushort smem[2 * 8192];
    ushort* Ks  = smem;
    ushort* Vts = smem + 8192;

    const int tid  = threadIdx.x;
    const int wave = tid >> 6, lane = tid & 63;
    const int l15 = lane & 15, quad = lane >> 4;
    const int bx = blockIdx.x;
    // q-tile in HIGH bits: the 8 q-blocks of one (b,h) are == mod 8 in
    // dispatch order -> same XCD -> K/V tiles shared in that L2.
    const int bh = bx & 127, h = bh & 15, b = bh >> 4;
    const int q0 = (bx >> 7) * 128;

    const ushort* Qg = Q + ((size_t)(b * 1024 + q0)) * 1024 + h * 64;
    const ushort* Kg = K + ((size_t)(b * 2048)) * 1024 + h * 64;
    const ushort* Vg = Vt + ((size_t)(b * 1024 + h * 64)) * 2048;

    // --- Q fragments straight to registers (B-frag: n=q=l15, k=quad*8+j)
    short8 bq[2][2];
#pragma unroll
    for (int qt = 0; qt < 2; ++qt) {
        int row = wave * 32 + qt * 16 + l15;
#pragma unroll
        for (int ks = 0; ks < 2; ++ks)
            bq[ks][qt] = *(const short8*)(Qg + (size_t)row * 1024 + ks * 32 + quad * 8);
    }

    f32x4 Oacc[4][2] = {};
    float l_run[2] = {0.f, 0.f};

    const int rig = lane >> 3;        // K staging: row in 8-row group
    const int scb8 = (lane & 7) ^ rig;
    const int riv = lane >> 4;        // V staging: row in 4-row group
    const int cb16 = lane & 15;

    for (int kv0 = 0; kv0 < 2048; kv0 += 128) {
        __syncthreads();   // previous iter's LDS reads complete
        // --- stage K [128 kv][64 d] and V^T [64 d][128 kv(pi-permuted)]
#pragma unroll
        for (int g = 0; g < 4; ++g) {
            int G = wave * 4 + g;
            gld_lds16(Kg + (size_t)(kv0 + G * 8 + rig) * 1024 + scb8 * 8, Ks + G * 512);
            int vrow = G * 4 + riv;
            int scv = cb16 ^ (vrow & 15);
            gld_lds16(Vg + (size_t)vrow * 2048 + kv0 + scv * 8, Vts + G * 512);
        }
        __syncthreads();   // drains vmcnt -> all staged data visible

        __builtin_amdgcn_s_setprio(1);
        // --- per kv-tile: S^T tile = K·Q^T, then exp2 + sum + pack at once
        unsigned pk[8][2][2];
#pragma unroll
        for (int kvt = 0; kvt < 8; ++kvt) {
            f32x4 s0 = {}, s1 = {};
#pragma unroll
            for (int ks = 0; ks < 2; ++ks) {
                int ck = ((ks * 4 + quad) ^ (l15 & 7)) * 8;   // swizzled chunk
                short8 ak = *(const short8*)(Ks + (kvt * 16 + l15) * 64 + ck);
                s0 = __builtin_amdgcn_mfma_f32_16x16x32_bf16(ak, bq[ks][0], s0, 0, 0, 0);
                s1 = __builtin_amdgcn_mfma_f32_16x16x32_bf16(ak, bq[ks][1], s1, 0, 0, 0);
            }
            float p0[4], p1[4];
#pragma unroll
            for (int rr = 0; rr < 4; ++rr) {
                p0[rr] = __builtin_amdgcn_exp2f(s0[rr]);
                p1[rr] = __builtin_amdgcn_exp2f(s1[rr]);
                l_run[0] += p0[rr];
                l_run[1] += p1[rr];
            }
            pk[kvt][0][0] = pack_bf2(p0[0], p0[1]);
            pk[kvt][0][1] = pack_bf2(p0[2], p0[3]);
            pk[kvt][1][0] = pack_bf2(p1[0], p1[1]);
            pk[kvt][1][1] = pack_bf2(p1[2], p1[3]);
        }

        // --- O^T += V^T · P^T : P^T B-frags straight from pk registers
#pragma unroll
        for (int sp = 0; sp < 4; ++sp) {
#pragma unroll
            for (int dt = 0; dt < 4; ++dt) {
                int cv = ((sp * 4 + quad) ^ l15) * 8;
                short8 av = *(const short8*)(Vts + (dt * 16 + l15) * 128 + cv);
#pragma unroll
                for (int qt = 0; qt < 2; ++qt) {
                    uint4v u = {pk[2 * sp][qt][0], pk[2 * sp][qt][1],
                                pk[2 * sp + 1][qt][0], pk[2 * sp + 1][qt][1]};
                    short8 bp = __builtin_bit_cast(short8, u);
                    Oacc[dt][qt] = __builtin_amdgcn_mfma_f32_16x16x32_bf16(av, bp, Oacc[dt][qt], 0, 0, 0);
                }
            }
        }
        __builtin_amdgcn_s_setprio(0);
    }

    // --- epilogue: reduce l across quads, O = (O^T)^T / l, packed 8B stores
#pragma unroll
    for (int qt = 0; qt < 2; ++qt) {
        float l = l_run[qt];
        l += __shfl_xor(l, 16);
        l += __shfl_xor(l, 32);
        float inv = 1.f / l;
        int qg = q0 + wave * 32 + qt * 16 + l15;
#pragma unroll
        for (int dt = 0; dt < 4; ++dt) {
            uint2 o;
            o.x = pack_bf2(Oacc[dt][qt][0] * inv, Oacc[dt][qt][1] * inv);
            o.y = pack_bf2(Oacc[dt][qt][2] * inv, Oacc[dt][qt][3] * inv);
            *(uint2*)(O + ((size_t)(b * 1024 + qg)) * 1024 + h * 64 + dt * 16 + quad * 4) = o;
        }
    }
}

// ---------------------------------------------------------------------------
extern "C" void kernel_launch(void* const* d_in, const int* in_sizes, int n_in,
                              void* d_out, int out_size, void* d_ws, size_t ws_size,
                              hipStream_t stream) {
    const float* latent = (const float*)d_in[0];
    const float* data   = (const float*)d_in[1];
    const float* wq     = (const float*)d_in[2];
    const float* bq     = (const float*)d_in[3];
    const float* wk     = (const float*)d_in[4];
    const float* bk     = (const float*)d_in[5];
    const float* wv     = (const float*)d_in[6];
    const float* bv     = (const float*)d_in[7];
    const float* wo     = (const float*)d_in[8];
    const float* bo     = (const float*)d_in[9];
    float* out = (float*)d_out;

    ushort* ws   = (ushort*)d_ws;
    ushort* wqT  = ws;
    ushort* wkT  = wqT + (1u << 20);
    ushort* wvT  = wkT + (1u << 20);
    ushort* woT  = wvT + (1u << 20);
    ushort* latB = woT + (1u << 20);
    ushort* datB = latB + (8u << 20);
    ushort* Qb   = datB + (16u << 20);
    ushort* Kb   = Qb + (8u << 20);
    ushort* Vtb  = Kb + (16u << 20);
    ushort* AO   = latB;               // alias: latB dead after proj_qkv
    // total ws footprint: 68M ushorts = 136 MB

    // fused prep: latent/data cvt + 4 weight transposes, one launch
    prep_fused<<<dim3(16384), 256, 0, stream>>>(latent, data, wq, wk, wv, wo,
                                                latB, datB, wqT, wkT, wvT, woT);

    const float qscale = 0.125f * 1.44269504088896340736f;  // HD^-0.5 * log2(e)
    // Q | K | V projections in one 640-block launch (256^2 8-phase GEMM + T1)
    proj_qkv<<<dim3(640), 512, 0, stream>>>(latB, datB, wqT, wkT, wvT,
                                            bq, bk, bv, Qb, Kb, Vtb, qscale);
    // fused attention -> AO [8192 x 1024] bf16
    attn_fused<<<dim3(1024), 256, 0, stream>>>(Qb, Kb, Vtb, AO);
    // out = AO @ wo + bo                             [8192 x 1024] f32
    gemm_bt<2><<<dim3(64, 8), 256, 0, stream>>>(AO, woT, bo, out, 1024, 1.0f);
}

// Round 5
// 354.546 us; speedup vs baseline: 1.0482x; 1.0281x over previous
//
#include <hip/hip_runtime.h>
#include <hip/hip_bf16.h>
#include <math.h>

// Problem: B=8, NQ=1024, NKV=2048, D=1024, H=16, HD=64, inner=1024.
// f32 storage in/out; bf16 MFMA compute with fp32 accumulation.
//
// ws layout (ushort elems):
//   wqT 1M | wkT 1M | wvT 1M | woT 1M | latB 8M | datB 16M | Q 8M | K 16M
//   | Vt 16M = 68M elems = 136 MB.  AO aliases latB (dead after proj_qkv).

using short8  = __attribute__((ext_vector_type(8))) short;
using f32x4   = __attribute__((ext_vector_type(4))) float;
using uint4v  = __attribute__((ext_vector_type(4))) unsigned int;

__device__ __forceinline__ ushort f2bf(float f) {
    unsigned u = __builtin_bit_cast(unsigned, f);
    u = (u + 0x7FFFu + ((u >> 16) & 1u)) >> 16;
    return (ushort)u;
}
// pack two f32 -> two bf16 (round-half-up) in one dword: lo | hi<<16
__device__ __forceinline__ unsigned pack_bf2(float lo, float hi) {
    unsigned ulo = __builtin_bit_cast(unsigned, lo) + 0x8000u;
    unsigned uhi = __builtin_bit_cast(unsigned, hi) + 0x8000u;
    return __builtin_amdgcn_perm(uhi, ulo, 0x07060302);
}

// async global->LDS, 16B/lane. LDS dest = wave-uniform base + lane*16;
// global address is per-lane (swizzle the SOURCE address, never the dest).
__device__ __forceinline__ void gld_lds16(const ushort* g, ushort* l) {
    __builtin_amdgcn_global_load_lds(
        (const __attribute__((address_space(1))) unsigned int*)(const void*)g,
        (__attribute__((address_space(3))) unsigned int*)(void*)l,
        16, 0, 0);
}

// ---------------------------------------------------------------------------
// Fused prep (one launch):
//   blocks [0, 4096)      : latent f32 -> bf16       (8M elems)
//   blocks [4096, 12288)  : data   f32 -> bf16       (16M elems)
//   blocks [12288, 16384) : weight transpose+cvt, 4 matrices x 1024 tiles
// ---------------------------------------------------------------------------
__global__ void prep_fused(const float* __restrict__ latent, const float* __restrict__ data,
                           const float* __restrict__ wq, const float* __restrict__ wk,
                           const float* __restrict__ wv, const float* __restrict__ wo,
                           ushort* __restrict__ latB, ushort* __restrict__ datB,
                           ushort* __restrict__ wqT, ushort* __restrict__ wkT,
                           ushort* __restrict__ wvT, ushort* __restrict__ woT) {
    __shared__ ushort tile[32][33];
    const int bx  = blockIdx.x;
    const int tid = threadIdx.x;
    if (bx < 12288) {
        const float* in = (bx < 4096) ? latent : data;
        ushort* out     = (bx < 4096) ? latB : datB;
        int idx = (bx < 4096) ? bx : bx - 4096;
        int i = (idx * 256 + tid) * 8;
        float4 a = *(const float4*)(in + i);
        float4 b = *(const float4*)(in + i + 4);
        short8 o;
        o[0] = (short)f2bf(a.x); o[1] = (short)f2bf(a.y);
        o[2] = (short)f2bf(a.z); o[3] = (short)f2bf(a.w);
        o[4] = (short)f2bf(b.x); o[5] = (short)f2bf(b.y);
        o[6] = (short)f2bf(b.z); o[7] = (short)f2bf(b.w);
        *(short8*)(out + i) = o;
        return;
    }
    int rem = bx - 12288;
    int z   = rem >> 10;             // matrix 0..3
    int bxx = rem & 31;              // x-tile
    int byy = (rem >> 5) & 31;       // y-tile
    const float* in = (z == 0) ? wq : (z == 1) ? wk : (z == 2) ? wv : wo;
    ushort* out     = (z == 0) ? wqT : (z == 1) ? wkT : (z == 2) ? wvT : woT;
    int tx = tid & 31, ty = tid >> 5;    // 32 x 8
    int x = bxx * 32 + tx;
    int y = byy * 32;
#pragma unroll
    for (int i = 0; i < 32; i += 8)
        tile[ty + i][tx] = f2bf(in[(size_t)(y + ty + i) * 1024 + x]);
    __syncthreads();
    int x2 = byy * 32 + tx;
    int y2 = bxx * 32;
#pragma unroll
    for (int i = 0; i < 32; i += 8)
        out[(size_t)(y2 + ty + i) * 1024 + x2] = tile[tx][ty + i];
}

// ---------------------------------------------------------------------------
// 256x256 8-phase GEMM (T2+T3+T4+T5), K=1024, ld=1024 for A and Bt.
// R5: tail-fill. 640 tiles at 1 block/CU was 3 rounds (3x37=111us) for 2.5
// rounds of work. Now: 512 full 256^2 tiles (rounds 1-2) + the last 128
// V-tiles split into 256 half-M (128x256) blocks that fill round 3 on all
// 256 CUs at ~0.55tau. Half body: same T-stack; all ds_reads in ph1 (A-half
// reuse per wave), per-iter loads 2+1+2+1=6 -> counted drain vmcnt(4)
// (same invariant as the proven vmcnt(6): at ph4's wait, all loads through
// this iter's ph1 = all of tile g+1 are complete).
// ---------------------------------------------------------------------------
template <int S>  // S = 64 for A halves (256-row), 32 for B halves
__device__ __forceinline__ void stage_half(const ushort* __restrict__ G, int rbase,
                                           ushort* tile, int H, int kcol,
                                           int wave, int lane) {
#pragma unroll
    for (int c = 0; c < 2; ++c) {
        int rho = c * 64 + wave * 8;                      // local row, 8-row group
        int gr0 = (rho / S) * (2 * S) + H * S + (rho % S); // global row in 256-tile
        int rig = lane >> 3;                               // row within group
        int q   = (lane & 7) ^ rig;                        // pre-swizzled src chunk
        gld_lds16(G + (size_t)(rbase + gr0 + rig) * 1024 + kcol + q * 8,
                  tile + gr0 * 64);
    }
}
// 128-row A tile: one 8-row-group load per wave covers a 64-row half.
__device__ __forceinline__ void stage_a128(const ushort* __restrict__ G, int rbase,
                                           ushort* tile, int H, int kcol,
                                           int wave, int lane) {
    int gr0 = H * 64 + wave * 8;
    int rig = lane >> 3;
    int q   = (lane & 7) ^ rig;
    gld_lds16(G + (size_t)(rbase + gr0 + rig) * 1024 + kcol + q * 8,
              tile + gr0 * 64);
}

__device__ __forceinline__ void gemm256_body(
        const ushort* __restrict__ A, const ushort* __restrict__ Bt,
        const float* __restrict__ bias, void* __restrict__ Cv,
        ushort* sm, float scale, int mode, int bm, int bn) {
    ushort* As0 = sm;
    ushort* Bs0 = sm + 16384;
    ushort* As1 = sm + 32768;
    ushort* Bs1 = sm + 49152;

    const int tid  = threadIdx.x;
    const int wave = tid >> 6, lane = tid & 63;
    const int l15 = lane & 15, quad = lane >> 4;
    const int wm = wave >> 2, wn = wave & 3;
    const int m0 = bm * 256, n0 = bn * 256;

    const int rA  = wm * 128 + l15;          // frag row base in A-tile
    const int rB  = wn * 64 + l15;           // frag row base in B-tile
    const int cq0 = quad ^ (l15 & 7);        // swizzled chunk, kk=0
    const int cq1 = (4 + quad) ^ (l15 & 7);  // swizzled chunk, kk=1

    // --- prologue: tile0 all 4 halves, then tile1 {A-H0, B-H1, A-H1}.
    // vmcnt(6) completes the oldest 8 loads = all of tile0.
    stage_half<64>(A,  m0, As0, 0, 0,  wave, lane);
    stage_half<32>(Bt, n0, Bs0, 0, 0,  wave, lane);
    stage_half<32>(Bt, n0, Bs0, 1, 0,  wave, lane);
    stage_half<64>(A,  m0, As0, 1, 0,  wave, lane);
    stage_half<64>(A,  m0, As1, 0, 64, wave, lane);
    stage_half<32>(Bt, n0, Bs1, 1, 64, wave, lane);
    stage_half<64>(A,  m0, As1, 1, 64, wave, lane);
    asm volatile("s_waitcnt vmcnt(6)" ::: "memory");
    __builtin_amdgcn_s_barrier();

    f32x4 acc[8][4] = {};

#define LDA(MH)                                                                   \
    _Pragma("unroll")                                                             \
    for (int mi = 0; mi < 4; ++mi) {                                              \
        a[mi][0] = *(const short8*)(Ac + (rA + (MH) * 64 + mi * 16) * 64 + cq0 * 8); \
        a[mi][1] = *(const short8*)(Ac + (rA + (MH) * 64 + mi * 16) * 64 + cq1 * 8); \
    }
#define LDB_ALL                                                                   \
    _Pragma("unroll")                                                             \
    for (int nj = 0; nj < 4; ++nj) {                                              \
        b[nj][0] = *(const short8*)(Bc + (rB + nj * 16) * 64 + cq0 * 8);          \
        b[nj][1] = *(const short8*)(Bc + (rB + nj * 16) * 64 + cq1 * 8);          \
    }
#define MFMA_PHASE(MB, NB)                                                        \
    __builtin_amdgcn_s_barrier();                                                 \
    asm volatile("s_waitcnt lgkmcnt(0)" ::: "memory");                            \
    __builtin_amdgcn_sched_barrier(0);                                            \
    __builtin_amdgcn_s_setprio(1);                                                \
    _Pragma("unroll")                                                             \
    for (int mi = 0; mi < 4; ++mi)                                                \
        _Pragma("unroll")                                                         \
        for (int ni = 0; ni < 2; ++ni)                                            \
            _Pragma("unroll")                                                     \
            for (int kk = 0; kk < 2; ++kk)                                        \
                acc[(MB) * 4 + mi][(NB) * 2 + ni] =                               \
                    __builtin_amdgcn_mfma_f32_16x16x32_bf16(                      \
                        a[mi][kk], b[(NB) * 2 + ni][kk],                          \
                        acc[(MB) * 4 + mi][(NB) * 2 + ni], 0, 0, 0);              \
    __builtin_amdgcn_s_setprio(0);                                                \
    __builtin_amdgcn_s_barrier();

#pragma unroll 2
    for (int g = 0; g < 16; ++g) {
        ushort* Ac = (g & 1) ? As1 : As0;
        ushort* Bc = (g & 1) ? Bs1 : Bs0;
        ushort* Bn = (g & 1) ? Bs0 : Bs1;
        const int k1 = ((g + 1) & 15) * 64;   // wrap: tail stages harmless
        const int k2 = ((g + 2) & 15) * 64;
        short8 a[4][2], b[4][2];

        // ---- phase 1: Q(m0,n0); all B frags; stage next-tile B-H0
        LDA(0) LDB_ALL
        stage_half<32>(Bt, n0, Bn, 0, k1, wave, lane);
        MFMA_PHASE(0, 0)

        // ---- phase 2: Q(m0,n1); no ds_reads; stage tile g+2 A-H0
        stage_half<64>(A, m0, Ac, 0, k2, wave, lane);
        MFMA_PHASE(0, 1)

        // ---- phase 3: Q(m1,n1); A second half; stage tile g+2 B-H1
        LDA(1)
        stage_half<32>(Bt, n0, Bc, 1, k2, wave, lane);
        MFMA_PHASE(1, 1)

        // ---- phase 4: Q(m1,n0); no ds_reads; stage; counted drain (never 0)
        stage_half<64>(A, m0, Ac, 1, k2, wave, lane);
        asm volatile("s_waitcnt vmcnt(6)" ::: "memory");
        MFMA_PHASE(1, 0)
    }
#undef LDA
#undef LDB_ALL
#undef MFMA_PHASE

    asm volatile("s_waitcnt vmcnt(0)" ::: "memory");

    // --- epilogue
    float bvv[4];
    int   cols[4];
#pragma unroll
    for (int n4 = 0; n4 < 4; ++n4) {
        cols[n4] = n0 + wn * 64 + n4 * 16 + l15;
        bvv[n4]  = bias[cols[n4]];
    }
#pragma unroll
    for (int m8 = 0; m8 < 8; ++m8) {
        int rbase = m0 + wm * 128 + m8 * 16 + quad * 4;
#pragma unroll
        for (int n4 = 0; n4 < 4; ++n4) {
            float v[4];
#pragma unroll
            for (int rr = 0; rr < 4; ++rr)
                v[rr] = (acc[m8][n4][rr] + bvv[n4]) * scale;
            if (mode == 1) {
                int kvl = rbase & 2047;
                int pos = (kvl & ~31) + ((kvl >> 2) & 3) * 8 + ((kvl >> 4) & 1) * 4;
                size_t base = ((size_t)((rbase >> 11) * 1024 + cols[n4])) * 2048 + pos;
                uint2 o;
                o.x = pack_bf2(v[0], v[1]);
                o.y = pack_bf2(v[2], v[3]);
                *(uint2*)((ushort*)Cv + base) = o;
            } else if (mode == 0) {
#pragma unroll
                for (int rr = 0; rr < 4; ++rr)
                    ((ushort*)Cv)[(size_t)(rbase + rr) * 1024 + cols[n4]] = f2bf(v[rr]);
            } else {
#pragma unroll
                for (int rr = 0; rr < 4; ++rr)
                    ((float*)Cv)[(size_t)(rbase + rr) * 1024 + cols[n4]] = v[rr];
            }
        }
    }
}

// --- 128x256 half-tile body (V projection, mode-1 epilogue only) ---
__device__ __forceinline__ void gemm128_body(
        const ushort* __restrict__ A, const ushort* __restrict__ Bt,
        const float* __restrict__ bias, ushort* __restrict__ Cv,
        ushort* sm, int m0, int n0) {
    ushort* As0 = sm;                 //  8192 ushorts (128x64)
    ushort* Bs0 = sm + 8192;          // 16384 ushorts (256x64)
    ushort* As1 = sm + 24576;
    ushort* Bs1 = sm + 32768;         // total 96 KiB of the 128 KiB block

    const int tid  = threadIdx.x;
    const int wave = tid >> 6, lane = tid & 63;
    const int l15 = lane & 15, quad = lane >> 4;
    const int wm = wave >> 2, wn = wave & 3;   // wave tile 64x64

    const int rA  = wm * 64 + l15;
    const int rB  = wn * 64 + l15;
    const int cq0 = quad ^ (l15 & 7);
    const int cq1 = (4 + quad) ^ (l15 & 7);

    // prologue: tile0 {A0,B0,B1,A1} (6 loads) + tile1 {A0,B1,A1} (4 loads);
    // vmcnt(4) completes the oldest 6 = all of tile0.
    stage_a128(A, m0, As0, 0, 0, wave, lane);
    stage_half<32>(Bt, n0, Bs0, 0, 0, wave, lane);
    stage_half<32>(Bt, n0, Bs0, 1, 0, wave, lane);
    stage_a128(A, m0, As0, 1, 0, wave, lane);
    stage_a128(A, m0, As1, 0, 64, wave, lane);
    stage_half<32>(Bt, n0, Bs1, 1, 64, wave, lane);
    stage_a128(A, m0, As1, 1, 64, wave, lane);
    asm volatile("s_waitcnt vmcnt(4)" ::: "memory");
    __builtin_amdgcn_s_barrier();

    f32x4 acc[4][4] = {};

#define MFMA_PHASE_N(NI)                                                          \
    __builtin_amdgcn_s_barrier();                                                 \
    asm volatile("s_waitcnt lgkmcnt(0)" ::: "memory");                            \
    __builtin_amdgcn_sched_barrier(0);                                            \
    __builtin_amdgcn_s_setprio(1);                                                \
    _Pragma("unroll")                                                             \
    for (int mi = 0; mi < 4; ++mi)                                                \
        _Pragma("unroll")                                                         \
        for (int kk = 0; kk < 2; ++kk)                                            \
            acc[mi][NI] = __builtin_amdgcn_mfma_f32_16x16x32_bf16(                \
                a[mi][kk], b[NI][kk], acc[mi][NI], 0, 0, 0);                      \
    __builtin_amdgcn_s_setprio(0);                                                \
    __builtin_amdgcn_s_barrier();

#pragma unroll 2
    for (int g = 0; g < 16; ++g) {
        ushort* Ac = (g & 1) ? As1 : As0;
        ushort* Bc = (g & 1) ? Bs1 : Bs0;
        ushort* Bn = (g & 1) ? Bs0 : Bs1;
        const int k1 = ((g + 1) & 15) * 64;
        const int k2 = ((g + 2) & 15) * 64;
        short8 a[4][2], b[4][2];

        // ---- phase 1: ALL ds_reads (wave wm only touches its own A half,
        // which is fully resident per the vmcnt(4) invariant); stage B-H0(g+1)
#pragma unroll
        for (int mi = 0; mi < 4; ++mi) {
            a[mi][0] = *(const short8*)(Ac + (rA + mi * 16) * 64 + cq0 * 8);
            a[mi][1] = *(const short8*)(Ac + (rA + mi * 16) * 64 + cq1 * 8);
        }
#pragma unroll
        for (int nj = 0; nj < 4; ++nj) {
            b[nj][0] = *(const short8*)(Bc + (rB + nj * 16) * 64 + cq0 * 8);
            b[nj][1] = *(const short8*)(Bc + (rB + nj * 16) * 64 + cq1 * 8);
        }
        stage_half<32>(Bt, n0, Bn, 0, k1, wave, lane);
        MFMA_PHASE_N(0)

        // ---- phase 2: stage A-H0(g+2) (A reads all done in ph1)
        stage_a128(A, m0, Ac, 0, k2, wave, lane);
        MFMA_PHASE_N(1)

        // ---- phase 3: stage B-H1(g+2)
        stage_half<32>(Bt, n0, Bc, 1, k2, wave, lane);
        MFMA_PHASE_N(2)

        // ---- phase 4: stage A-H1(g+2); counted drain vmcnt(4)
        stage_a128(A, m0, Ac, 1, k2, wave, lane);
        asm volatile("s_waitcnt vmcnt(4)" ::: "memory");
        MFMA_PHASE_N(3)
    }
#undef MFMA_PHASE_N

    asm volatile("s_waitcnt vmcnt(0)" ::: "memory");

    // --- mode-1 epilogue (pi-permuted Vt store)
    float bvv[4];
    int   cols[4];
#pragma unroll
    for (int n4 = 0; n4 < 4; ++n4) {
        cols[n4] = n0 + wn * 64 + n4 * 16 + l15;
        bvv[n4]  = bias[cols[n4]];
    }
#pragma unroll
    for (int m4 = 0; m4 < 4; ++m4) {
        int rbase = m0 + wm * 64 + m4 * 16 + quad * 4;
#pragma unroll
        for (int n4 = 0; n4 < 4; ++n4) {
            float v[4];
#pragma unroll
            for (int rr = 0; rr < 4; ++rr)
                v[rr] = acc[m4][n4][rr] + bvv[n4];
            int kvl = rbase & 2047;
            int pos = (kvl & ~31) + ((kvl >> 2) & 3) * 8 + ((kvl >> 4) & 1) * 4;
            size_t base = ((size_t)((rbase >> 11) * 1024 + cols[n4])) * 2048 + pos;
            uint2 o;
            o.x = pack_bf2(v[0], v[1]);
            o.y = pack_bf2(v[2], v[3]);
            *(uint2*)(Cv + base) = o;
        }
    }
}

// Fused Q/K/V projections, 768 blocks, 1 block/CU:
//   rounds 1-2: 512 full 256^2 tiles (Q:128, K:256, V-lower:128)
//   round 3   : 256 half-M 128x256 blocks (V-upper 128 tiles) on ALL CUs
// XCD swizzle applied within each set (512=8x64, 256=8x32) to preserve the
// round structure while keeping A-panel sharers on one XCD's L2.
__global__ __launch_bounds__(512, 2) void proj_qkv(
        const ushort* __restrict__ latB, const ushort* __restrict__ datB,
        const ushort* __restrict__ wqT, const ushort* __restrict__ wkT,
        const ushort* __restrict__ wvT,
        const float* __restrict__ bq, const float* __restrict__ bk,
        const float* __restrict__ bv,
        ushort* __restrict__ Qb, ushort* __restrict__ Kb, ushort* __restrict__ Vtb,
        float qscale) {
    __shared__ __align__(16) ushort sm[65536];   // 128 KiB
    int bx = blockIdx.x;
    if (bx < 512) {
        int bid = (bx & 7) * 64 + (bx >> 3);
        const ushort* A; const ushort* W; const float* bias;
        void* C; float sc; int mode, idx;
        if (bid < 128)      { A = latB; W = wqT; bias = bq; C = Qb;  sc = qscale; mode = 0; idx = bid; }
        else if (bid < 384) { A = datB; W = wkT; bias = bk; C = Kb;  sc = 1.f;    mode = 0; idx = bid - 128; }
        else                { A = datB; W = wvT; bias = bv; C = Vtb; sc = 1.f;    mode = 1; idx = bid - 384; }
        gemm256_body(A, W, bias, C, sm, sc, mode, idx >> 2, idx & 3);
    } else {
        int t  = bx - 512;
        int tt = (t & 7) * 32 + (t >> 3);
        int vtile = 128 + (tt >> 1);
        int mhalf = tt & 1;
        int m0 = (vtile >> 2) * 256 + mhalf * 128;
        int n0 = (vtile & 3) * 256;
        gemm128_body(datB, wvT, bv, Vtb, sm, m0, n0);
    }
}

// ---------------------------------------------------------------------------
// 128^2-tile GEMM (proven ~500 TF class at K=1024) — O projection only.
// ---------------------------------------------------------------------------
template <int MODE>
__global__ void gemm_bt(const ushort* __restrict__ A, const ushort* __restrict__ Bt,
                        const float* __restrict__ bias, void* __restrict__ Cv,
                        int K, float scale) {
    __shared__ __align__(16) ushort As[128 * 32];
    __shared__ __align__(16) ushort Bs[128 * 32];
    const int tid  = threadIdx.x;
    const int wave = tid >> 6, lane = tid & 63;
    const int l15 = lane & 15, quad = lane >> 4;
    const int wm = wave & 1, wn = wave >> 1;
    const int m0 = blockIdx.x * 128;
    const int n0 = blockIdx.y * 128;

    f32x4 acc[4][4] = {};

    for (int k0 = 0; k0 < K; k0 += 32) {
        __syncthreads();
#pragma unroll
        for (int i = 0; i < 2; ++i) {
            int f   = (i * 256 + tid) * 8;
            int row = f >> 5, col = f & 31;
            gld_lds16(A  + (size_t)(m0 + row) * K + k0 + col, As + (i * 256 + wave * 64) * 8);
            gld_lds16(Bt + (size_t)(n0 + row) * K + k0 + col, Bs + (i * 256 + wave * 64) * 8);
        }
        __syncthreads();

        short8 a[4], b[4];
#pragma unroll
        for (int mi = 0; mi < 4; ++mi)
            a[mi] = *(const short8*)(As + (wm * 64 + mi * 16 + l15) * 32 + quad * 8);
#pragma unroll
        for (int ni = 0; ni < 4; ++ni)
            b[ni] = *(const short8*)(Bs + (wn * 64 + ni * 16 + l15) * 32 + quad * 8);
#pragma unroll
        for (int mi = 0; mi < 4; ++mi)
#pragma unroll
            for (int ni = 0; ni < 4; ++ni)
                acc[mi][ni] = __builtin_amdgcn_mfma_f32_16x16x32_bf16(a[mi], b[ni], acc[mi][ni], 0, 0, 0);
    }

    float bv[4];
    int   cols[4];
#pragma unroll
    for (int ni = 0; ni < 4; ++ni) {
        cols[ni] = n0 + wn * 64 + ni * 16 + l15;
        bv[ni]   = bias[cols[ni]];
    }
#pragma unroll
    for (int mi = 0; mi < 4; ++mi) {
        int rbase = m0 + wm * 64 + mi * 16 + quad * 4;
#pragma unroll
        for (int ni = 0; ni < 4; ++ni) {
            float v[4];
#pragma unroll
            for (int rr = 0; rr < 4; ++rr)
                v[rr] = (acc[mi][ni][rr] + bv[ni]) * scale;
            if (MODE == 1) {
                int kvl = rbase & 2047;
                int pos = (kvl & ~31) + ((kvl >> 2) & 3) * 8 + ((kvl >> 4) & 1) * 4;
                size_t base = ((size_t)((rbase >> 11) * 1024 + cols[ni])) * 2048 + pos;
                uint2 o;
                o.x = pack_bf2(v[0], v[1]);
                o.y = pack_bf2(v[2], v[3]);
                *(uint2*)((ushort*)Cv + base) = o;
            } else {
#pragma unroll
                for (int rr = 0; rr < 4; ++rr) {
                    int row = rbase + rr;
                    if (MODE == 0)
                        ((ushort*)Cv)[(size_t)row * 1024 + cols[ni]] = f2bf(v[rr]);
                    else
                        ((float*)Cv)[(size_t)row * 1024 + cols[ni]] = v[rr];
                }
            }
        }
    }
}

// ---------------------------------------------------------------------------
// Fused flash attention, S^T formulation, fixed-max base-2 softmax.
// (proven 89us structure; setprio kept from R4 — neutral-to-slightly-positive)
// ---------------------------------------------------------------------------
__global__ __launch_bounds__(256, 4) void attn_fused(const ushort* __restrict__ Q,
                                                     const ushort* __restrict__ K,
                                                     const ushort* __restrict__ Vt,
                                                     ushort* __restrict__ O) {
    __shared__ __align__(16) ushort smem[2 * 8192];
    ushort* Ks  = smem;
    ushort* Vts = smem + 8192;

    const int tid  = threadIdx.x;
    const int wave = tid >> 6, lane = tid & 63;
    const int l15 = lane & 15, quad = lane >> 4;
    const int bx = blockIdx.x;
    const int bh = bx & 127, h = bh & 15, b = bh >> 4;
    const int q0 = (bx >> 7) * 128;

    const ushort* Qg = Q + ((size_t)(b * 1024 + q0)) * 1024 + h * 64;
    const ushort* Kg = K + ((size_t)(b * 2048)) * 1024 + h * 64;
    const ushort* Vg = Vt + ((size_t)(b * 1024 + h * 64)) * 2048;

    short8 bq[2][2];
#pragma unroll
    for (int qt = 0; qt < 2; ++qt) {
        int row = wave * 32 + qt * 16 + l15;
#pragma unroll
        for (int ks = 0; ks < 2; ++ks)
            bq[ks][qt] = *(const short8*)(Qg + (size_t)row * 1024 + ks * 32 + quad * 8);
    }

    f32x4 Oacc[4][2] = {};
    float l_run[2] = {0.f, 0.f};

    const int rig = lane >> 3;
    const int scb8 = (lane & 7) ^ rig;
    const int riv = lane >> 4;
    const int cb16 = lane & 15;

    for (int kv0 = 0; kv0 < 2048; kv0 += 128) {
        __syncthreads();
#pragma unroll
        for (int g = 0; g < 4; ++g) {
            int G = wave * 4 + g;
            gld_lds16(Kg + (size_t)(kv0 + G * 8 + rig) * 1024 + scb8 * 8, Ks + G * 512);
            int vrow = G * 4 + riv;
            int scv = cb16 ^ (vrow & 15);
            gld_lds16(Vg + (size_t)vrow * 2048 + kv0 + scv * 8, Vts + G * 512);
        }
        __syncthreads();

        __builtin_amdgcn_s_setprio(1);
        unsigned pk[8][2][2];
#pragma unroll
        for (int kvt = 0; kvt < 8; ++kvt) {
            f32x4 s0 = {}, s1 = {};
#pragma unroll
            for (int ks = 0; ks < 2; ++ks) {
                int ck = ((ks * 4 + quad) ^ (l15 & 7)) * 8;
                short8 ak = *(const short8*)(Ks + (kvt * 16 + l15) * 64 + ck);
                s0 = __builtin_amdgcn_mfma_f32_16x16x32_bf16(ak, bq[ks][0], s0, 0, 0, 0);
                s1 = __builtin_amdgcn_mfma_f32_16x16x32_bf16(ak, bq[ks][1], s1, 0, 0, 0);
            }
            float p0[4], p1[4];
#pragma unroll
            for (int rr = 0; rr < 4; ++rr) {
                p0[rr] = __builtin_amdgcn_exp2f(s0[rr]);
                p1[rr] = __builtin_amdgcn_exp2f(s1[rr]);
                l_run[0] += p0[rr];
                l_run[1] += p1[rr];
            }
            pk[kvt][0][0] = pack_bf2(p0[0], p0[1]);
            pk[kvt][0][1] = pack_bf2(p0[2], p0[3]);
            pk[kvt][1][0] = pack_bf2(p1[0], p1[1]);
            pk[kvt][1][1] = pack_bf2(p1[2], p1[3]);
        }

#pragma unroll
        for (int sp = 0; sp < 4; ++sp) {
#pragma unroll
            for (int dt = 0; dt < 4; ++dt) {
                int cv = ((sp * 4 + quad) ^ l15) * 8;
                short8 av = *(const short8*)(Vts + (dt * 16 + l15) * 128 + cv);
#pragma unroll
                for (int qt = 0; qt < 2; ++qt) {
                    uint4v u = {pk[2 * sp][qt][0], pk[2 * sp][qt][1],
                                pk[2 * sp + 1][qt][0], pk[2 * sp + 1][qt][1]};
                    short8 bp = __builtin_bit_cast(short8, u);
                    Oacc[dt][qt] = __builtin_amdgcn_mfma_f32_16x16x32_bf16(av, bp, Oacc[dt][qt], 0, 0, 0);
                }
            }
        }
        __builtin_amdgcn_s_setprio(0);
    }

#pragma unroll
    for (int qt = 0; qt < 2; ++qt) {
        float l = l_run[qt];
        l += __shfl_xor(l, 16);
        l += __shfl_xor(l, 32);
        float inv = 1.f / l;
        int qg = q0 + wave * 32 + qt * 16 + l15;
#pragma unroll
        for (int dt = 0; dt < 4; ++dt) {
            uint2 o;
            o.x = pack_bf2(Oacc[dt][qt][0] * inv, Oacc[dt][qt][1] * inv);
            o.y = pack_bf2(Oacc[dt][qt][2] * inv, Oacc[dt][qt][3] * inv);
            *(uint2*)(O + ((size_t)(b * 1024 + qg)) * 1024 + h * 64 + dt * 16 + quad * 4) = o;
        }
    }
}

// ---------------------------------------------------------------------------
extern "C" void kernel_launch(void* const* d_in, const int* in_sizes, int n_in,
                              void* d_out, int out_size, void* d_ws, size_t ws_size,
                              hipStream_t stream) {
    const float* latent = (const float*)d_in[0];
    const float* data   = (const float*)d_in[1];
    const float* wq     = (const float*)d_in[2];
    const float* bq     = (const float*)d_in[3];
    const float* wk     = (const float*)d_in[4];
    const float* bk     = (const float*)d_in[5];
    const float* wv     = (const float*)d_in[6];
    const float* bv     = (const float*)d_in[7];
    const float* wo     = (const float*)d_in[8];
    const float* bo     = (const float*)d_in[9];
    float* out = (float*)d_out;

    ushort* ws   = (ushort*)d_ws;
    ushort* wqT  = ws;
    ushort* wkT  = wqT + (1u << 20);
    ushort* wvT  = wkT + (1u << 20);
    ushort* woT  = wvT + (1u << 20);
    ushort* latB = woT + (1u << 20);
    ushort* datB = latB + (8u << 20);
    ushort* Qb   = datB + (16u << 20);
    ushort* Kb   = Qb + (8u << 20);
    ushort* Vtb  = Kb + (16u << 20);
    ushort* AO   = latB;               // alias: latB dead after proj_qkv
    // total ws footprint: 68M ushorts = 136 MB

    // fused prep: latent/data cvt + 4 weight transposes, one launch
    prep_fused<<<dim3(16384), 256, 0, stream>>>(latent, data, wq, wk, wv, wo,
                                                latB, datB, wqT, wkT, wvT, woT);

    const float qscale = 0.125f * 1.44269504088896340736f;  // HD^-0.5 * log2(e)
    // Q | K | V projections, 768 blocks (512 full + 256 tail-fill halves)
    proj_qkv<<<dim3(768), 512, 0, stream>>>(latB, datB, wqT, wkT, wvT,
                                            bq, bk, bv, Qb, Kb, Vtb, qscale);
    // fused attention -> AO [8192 x 1024] bf16
    attn_fused<<<dim3(1024), 256, 0, stream>>>(Qb, Kb, Vtb, AO);
    // out = AO @ wo + bo                             [8192 x 1024] f32
    gemm_bt<2><<<dim3(64, 8), 256, 0, stream>>>(AO, woT, bo, out, 1024, 1.0f);
}

// Round 6
// 352.758 us; speedup vs baseline: 1.0535x; 1.0051x over previous
//
#include <hip/hip_runtime.h>
#include <hip/hip_bf16.h>
#include <math.h>

// Problem: B=8, NQ=1024, NKV=2048, D=1024, H=16, HD=64, inner=1024.
// f32 storage in/out; bf16 MFMA compute with fp32 accumulation.
//
// ws layout (ushort elems):
//   wqT 1M | wkT 1M | wvT 1M | woT 1M | latB 8M | datB 16M | Q 8M | K 16M
//   | Vt 16M = 68M elems = 136 MB.  AO aliases latB (dead after proj_qkv).

using short8  = __attribute__((ext_vector_type(8))) short;
using f32x4   = __attribute__((ext_vector_type(4))) float;
using uint4v  = __attribute__((ext_vector_type(4))) unsigned int;

__device__ __forceinline__ ushort f2bf(float f) {
    unsigned u = __builtin_bit_cast(unsigned, f);
    u = (u + 0x7FFFu + ((u >> 16) & 1u)) >> 16;
    return (ushort)u;
}
// pack two f32 -> two bf16 (round-half-up) in one dword: lo | hi<<16
__device__ __forceinline__ unsigned pack_bf2(float lo, float hi) {
    unsigned ulo = __builtin_bit_cast(unsigned, lo) + 0x8000u;
    unsigned uhi = __builtin_bit_cast(unsigned, hi) + 0x8000u;
    return __builtin_amdgcn_perm(uhi, ulo, 0x07060302);
}

// async global->LDS, 16B/lane. LDS dest = wave-uniform base + lane*16;
// global address is per-lane (swizzle the SOURCE address, never the dest).
__device__ __forceinline__ void gld_lds16(const ushort* g, ushort* l) {
    __builtin_amdgcn_global_load_lds(
        (const __attribute__((address_space(1))) unsigned int*)(const void*)g,
        (__attribute__((address_space(3))) unsigned int*)(void*)l,
        16, 0, 0);
}

// ---------------------------------------------------------------------------
// Fused prep (one launch):
//   blocks [0, 4096)      : latent f32 -> bf16       (8M elems)
//   blocks [4096, 12288)  : data   f32 -> bf16       (16M elems)
//   blocks [12288, 16384) : weight transpose+cvt, 4 matrices x 1024 tiles
// ---------------------------------------------------------------------------
__global__ void prep_fused(const float* __restrict__ latent, const float* __restrict__ data,
                           const float* __restrict__ wq, const float* __restrict__ wk,
                           const float* __restrict__ wv, const float* __restrict__ wo,
                           ushort* __restrict__ latB, ushort* __restrict__ datB,
                           ushort* __restrict__ wqT, ushort* __restrict__ wkT,
                           ushort* __restrict__ wvT, ushort* __restrict__ woT) {
    __shared__ ushort tile[32][33];
    const int bx  = blockIdx.x;
    const int tid = threadIdx.x;
    if (bx < 12288) {
        const float* in = (bx < 4096) ? latent : data;
        ushort* out     = (bx < 4096) ? latB : datB;
        int idx = (bx < 4096) ? bx : bx - 4096;
        int i = (idx * 256 + tid) * 8;
        float4 a = *(const float4*)(in + i);
        float4 b = *(const float4*)(in + i + 4);
        short8 o;
        o[0] = (short)f2bf(a.x); o[1] = (short)f2bf(a.y);
        o[2] = (short)f2bf(a.z); o[3] = (short)f2bf(a.w);
        o[4] = (short)f2bf(b.x); o[5] = (short)f2bf(b.y);
        o[6] = (short)f2bf(b.z); o[7] = (short)f2bf(b.w);
        *(short8*)(out + i) = o;
        return;
    }
    int rem = bx - 12288;
    int z   = rem >> 10;             // matrix 0..3
    int bxx = rem & 31;              // x-tile
    int byy = (rem >> 5) & 31;       // y-tile
    const float* in = (z == 0) ? wq : (z == 1) ? wk : (z == 2) ? wv : wo;
    ushort* out     = (z == 0) ? wqT : (z == 1) ? wkT : (z == 2) ? wvT : woT;
    int tx = tid & 31, ty = tid >> 5;    // 32 x 8
    int x = bxx * 32 + tx;
    int y = byy * 32;
#pragma unroll
    for (int i = 0; i < 32; i += 8)
        tile[ty + i][tx] = f2bf(in[(size_t)(y + ty + i) * 1024 + x]);
    __syncthreads();
    int x2 = byy * 32 + tx;
    int y2 = bxx * 32;
#pragma unroll
    for (int i = 0; i < 32; i += 8)
        out[(size_t)(y2 + ty + i) * 1024 + x2] = tile[tx][ty + i];
}

// ---------------------------------------------------------------------------
// 256x256 8-phase GEMM (T2+T3+T4+T5), K=1024, ld=1024 for A and Bt.
// ---------------------------------------------------------------------------
template <int S>  // S = 64 for A halves (256-row), 32 for B halves
__device__ __forceinline__ void stage_half(const ushort* __restrict__ G, int rbase,
                                           ushort* tile, int H, int kcol,
                                           int wave, int lane) {
#pragma unroll
    for (int c = 0; c < 2; ++c) {
        int rho = c * 64 + wave * 8;                      // local row, 8-row group
        int gr0 = (rho / S) * (2 * S) + H * S + (rho % S); // global row in 256-tile
        int rig = lane >> 3;                               // row within group
        int q   = (lane & 7) ^ rig;                        // pre-swizzled src chunk
        gld_lds16(G + (size_t)(rbase + gr0 + rig) * 1024 + kcol + q * 8,
                  tile + gr0 * 64);
    }
}
// 128-row A tile: one 8-row-group load per wave covers a 64-row half.
__device__ __forceinline__ void stage_a128(const ushort* __restrict__ G, int rbase,
                                           ushort* tile, int H, int kcol,
                                           int wave, int lane) {
    int gr0 = H * 64 + wave * 8;
    int rig = lane >> 3;
    int q   = (lane & 7) ^ rig;
    gld_lds16(G + (size_t)(rbase + gr0 + rig) * 1024 + kcol + q * 8,
              tile + gr0 * 64);
}

__device__ __forceinline__ void gemm256_body(
        const ushort* __restrict__ A, const ushort* __restrict__ Bt,
        const float* __restrict__ bias, void* __restrict__ Cv,
        ushort* sm, float scale, int mode, int bm, int bn) {
    ushort* As0 = sm;
    ushort* Bs0 = sm + 16384;
    ushort* As1 = sm + 32768;
    ushort* Bs1 = sm + 49152;

    const int tid  = threadIdx.x;
    const int wave = tid >> 6, lane = tid & 63;
    const int l15 = lane & 15, quad = lane >> 4;
    const int wm = wave >> 2, wn = wave & 3;
    const int m0 = bm * 256, n0 = bn * 256;

    const int rA  = wm * 128 + l15;          // frag row base in A-tile
    const int rB  = wn * 64 + l15;           // frag row base in B-tile
    const int cq0 = quad ^ (l15 & 7);        // swizzled chunk, kk=0
    const int cq1 = (4 + quad) ^ (l15 & 7);  // swizzled chunk, kk=1

    // --- prologue: tile0 all 4 halves, then tile1 {A-H0, B-H1, A-H1}.
    // vmcnt(6) completes the oldest 8 loads = all of tile0.
    stage_half<64>(A,  m0, As0, 0, 0,  wave, lane);
    stage_half<32>(Bt, n0, Bs0, 0, 0,  wave, lane);
    stage_half<32>(Bt, n0, Bs0, 1, 0,  wave, lane);
    stage_half<64>(A,  m0, As0, 1, 0,  wave, lane);
    stage_half<64>(A,  m0, As1, 0, 64, wave, lane);
    stage_half<32>(Bt, n0, Bs1, 1, 64, wave, lane);
    stage_half<64>(A,  m0, As1, 1, 64, wave, lane);
    asm volatile("s_waitcnt vmcnt(6)" ::: "memory");
    __builtin_amdgcn_s_barrier();

    f32x4 acc[8][4] = {};

#define LDA(MH)                                                                   \
    _Pragma("unroll")                                                             \
    for (int mi = 0; mi < 4; ++mi) {                                              \
        a[mi][0] = *(const short8*)(Ac + (rA + (MH) * 64 + mi * 16) * 64 + cq0 * 8); \
        a[mi][1] = *(const short8*)(Ac + (rA + (MH) * 64 + mi * 16) * 64 + cq1 * 8); \
    }
#define LDB_ALL                                                                   \
    _Pragma("unroll")                                                             \
    for (int nj = 0; nj < 4; ++nj) {                                              \
        b[nj][0] = *(const short8*)(Bc + (rB + nj * 16) * 64 + cq0 * 8);          \
        b[nj][1] = *(const short8*)(Bc + (rB + nj * 16) * 64 + cq1 * 8);          \
    }
#define MFMA_PHASE(MB, NB)                                                        \
    __builtin_amdgcn_s_barrier();                                                 \
    asm volatile("s_waitcnt lgkmcnt(0)" ::: "memory");                            \
    __builtin_amdgcn_sched_barrier(0);                                            \
    __builtin_amdgcn_s_setprio(1);                                                \
    _Pragma("unroll")                                                             \
    for (int mi = 0; mi < 4; ++mi)                                                \
        _Pragma("unroll")                                                         \
        for (int ni = 0; ni < 2; ++ni)                                            \
            _Pragma("unroll")                                                     \
            for (int kk = 0; kk < 2; ++kk)                                        \
                acc[(MB) * 4 + mi][(NB) * 2 + ni] =                               \
                    __builtin_amdgcn_mfma_f32_16x16x32_bf16(                      \
                        a[mi][kk], b[(NB) * 2 + ni][kk],                          \
                        acc[(MB) * 4 + mi][(NB) * 2 + ni], 0, 0, 0);              \
    __builtin_amdgcn_s_setprio(0);                                                \
    __builtin_amdgcn_s_barrier();

#pragma unroll 2
    for (int g = 0; g < 16; ++g) {
        ushort* Ac = (g & 1) ? As1 : As0;
        ushort* Bc = (g & 1) ? Bs1 : Bs0;
        ushort* Bn = (g & 1) ? Bs0 : Bs1;
        const int k1 = ((g + 1) & 15) * 64;   // wrap: tail stages harmless
        const int k2 = ((g + 2) & 15) * 64;
        short8 a[4][2], b[4][2];

        // ---- phase 1: Q(m0,n0); all B frags; stage next-tile B-H0
        LDA(0) LDB_ALL
        stage_half<32>(Bt, n0, Bn, 0, k1, wave, lane);
        MFMA_PHASE(0, 0)

        // ---- phase 2: Q(m0,n1); no ds_reads; stage tile g+2 A-H0
        stage_half<64>(A, m0, Ac, 0, k2, wave, lane);
        MFMA_PHASE(0, 1)

        // ---- phase 3: Q(m1,n1); A second half; stage tile g+2 B-H1
        LDA(1)
        stage_half<32>(Bt, n0, Bc, 1, k2, wave, lane);
        MFMA_PHASE(1, 1)

        // ---- phase 4: Q(m1,n0); no ds_reads; stage; counted drain (never 0)
        stage_half<64>(A, m0, Ac, 1, k2, wave, lane);
        asm volatile("s_waitcnt vmcnt(6)" ::: "memory");
        MFMA_PHASE(1, 0)
    }
#undef LDA
#undef LDB_ALL
#undef MFMA_PHASE

    asm volatile("s_waitcnt vmcnt(0)" ::: "memory");

    // --- epilogue
    float bvv[4];
    int   cols[4];
#pragma unroll
    for (int n4 = 0; n4 < 4; ++n4) {
        cols[n4] = n0 + wn * 64 + n4 * 16 + l15;
        bvv[n4]  = bias[cols[n4]];
    }
#pragma unroll
    for (int m8 = 0; m8 < 8; ++m8) {
        int rbase = m0 + wm * 128 + m8 * 16 + quad * 4;
#pragma unroll
        for (int n4 = 0; n4 < 4; ++n4) {
            float v[4];
#pragma unroll
            for (int rr = 0; rr < 4; ++rr)
                v[rr] = (acc[m8][n4][rr] + bvv[n4]) * scale;
            if (mode == 1) {
                int kvl = rbase & 2047;
                int pos = (kvl & ~31) + ((kvl >> 2) & 3) * 8 + ((kvl >> 4) & 1) * 4;
                size_t base = ((size_t)((rbase >> 11) * 1024 + cols[n4])) * 2048 + pos;
                uint2 o;
                o.x = pack_bf2(v[0], v[1]);
                o.y = pack_bf2(v[2], v[3]);
                *(uint2*)((ushort*)Cv + base) = o;
            } else if (mode == 0) {
#pragma unroll
                for (int rr = 0; rr < 4; ++rr)
                    ((ushort*)Cv)[(size_t)(rbase + rr) * 1024 + cols[n4]] = f2bf(v[rr]);
            } else {
#pragma unroll
                for (int rr = 0; rr < 4; ++rr)
                    ((float*)Cv)[(size_t)(rbase + rr) * 1024 + cols[n4]] = v[rr];
            }
        }
    }
}

// --- 128x256 half-tile body. mode 1: pi-permuted bf16 Vt store; mode 2:
// f32 row-major store (O projection). Proven in R5's proj tail (~23us/round
// of 256 blocks). Counted drain vmcnt(4): per-iter loads 2+1+2+1=6; at ph4's
// wait everything through this iter's ph1 (= all of tile g+1) is complete.
__device__ __forceinline__ void gemm128_body(
        const ushort* __restrict__ A, const ushort* __restrict__ Bt,
        const float* __restrict__ bias, void* __restrict__ Cv,
        ushort* sm, int m0, int n0, int mode) {
    ushort* As0 = sm;                 //  8192 ushorts (128x64)
    ushort* Bs0 = sm + 8192;          // 16384 ushorts (256x64)
    ushort* As1 = sm + 24576;
    ushort* Bs1 = sm + 32768;         // total 96 KiB

    const int tid  = threadIdx.x;
    const int wave = tid >> 6, lane = tid & 63;
    const int l15 = lane & 15, quad = lane >> 4;
    const int wm = wave >> 2, wn = wave & 3;   // wave tile 64x64

    const int rA  = wm * 64 + l15;
    const int rB  = wn * 64 + l15;
    const int cq0 = quad ^ (l15 & 7);
    const int cq1 = (4 + quad) ^ (l15 & 7);

    // prologue: tile0 {A0,B0,B1,A1} (6 loads) + tile1 {A0,B1,A1} (4 loads);
    // vmcnt(4) completes the oldest 6 = all of tile0.
    stage_a128(A, m0, As0, 0, 0, wave, lane);
    stage_half<32>(Bt, n0, Bs0, 0, 0, wave, lane);
    stage_half<32>(Bt, n0, Bs0, 1, 0, wave, lane);
    stage_a128(A, m0, As0, 1, 0, wave, lane);
    stage_a128(A, m0, As1, 0, 64, wave, lane);
    stage_half<32>(Bt, n0, Bs1, 1, 64, wave, lane);
    stage_a128(A, m0, As1, 1, 64, wave, lane);
    asm volatile("s_waitcnt vmcnt(4)" ::: "memory");
    __builtin_amdgcn_s_barrier();

    f32x4 acc[4][4] = {};

#define MFMA_PHASE_N(NI)                                                          \
    __builtin_amdgcn_s_barrier();                                                 \
    asm volatile("s_waitcnt lgkmcnt(0)" ::: "memory");                            \
    __builtin_amdgcn_sched_barrier(0);                                            \
    __builtin_amdgcn_s_setprio(1);                                                \
    _Pragma("unroll")                                                             \
    for (int mi = 0; mi < 4; ++mi)                                                \
        _Pragma("unroll")                                                         \
        for (int kk = 0; kk < 2; ++kk)                                            \
            acc[mi][NI] = __builtin_amdgcn_mfma_f32_16x16x32_bf16(                \
                a[mi][kk], b[NI][kk], acc[mi][NI], 0, 0, 0);                      \
    __builtin_amdgcn_s_setprio(0);                                                \
    __builtin_amdgcn_s_barrier();

#pragma unroll 2
    for (int g = 0; g < 16; ++g) {
        ushort* Ac = (g & 1) ? As1 : As0;
        ushort* Bc = (g & 1) ? Bs1 : Bs0;
        ushort* Bn = (g & 1) ? Bs0 : Bs1;
        const int k1 = ((g + 1) & 15) * 64;
        const int k2 = ((g + 2) & 15) * 64;
        short8 a[4][2], b[4][2];

        // ---- phase 1: ALL ds_reads; stage B-H0(g+1)
#pragma unroll
        for (int mi = 0; mi < 4; ++mi) {
            a[mi][0] = *(const short8*)(Ac + (rA + mi * 16) * 64 + cq0 * 8);
            a[mi][1] = *(const short8*)(Ac + (rA + mi * 16) * 64 + cq1 * 8);
        }
#pragma unroll
        for (int nj = 0; nj < 4; ++nj) {
            b[nj][0] = *(const short8*)(Bc + (rB + nj * 16) * 64 + cq0 * 8);
            b[nj][1] = *(const short8*)(Bc + (rB + nj * 16) * 64 + cq1 * 8);
        }
        stage_half<32>(Bt, n0, Bn, 0, k1, wave, lane);
        MFMA_PHASE_N(0)

        // ---- phase 2: stage A-H0(g+2)
        stage_a128(A, m0, Ac, 0, k2, wave, lane);
        MFMA_PHASE_N(1)

        // ---- phase 3: stage B-H1(g+2)
        stage_half<32>(Bt, n0, Bc, 1, k2, wave, lane);
        MFMA_PHASE_N(2)

        // ---- phase 4: stage A-H1(g+2); counted drain vmcnt(4)
        stage_a128(A, m0, Ac, 1, k2, wave, lane);
        asm volatile("s_waitcnt vmcnt(4)" ::: "memory");
        MFMA_PHASE_N(3)
    }
#undef MFMA_PHASE_N

    asm volatile("s_waitcnt vmcnt(0)" ::: "memory");

    // --- epilogue
    float bvv[4];
    int   cols[4];
#pragma unroll
    for (int n4 = 0; n4 < 4; ++n4) {
        cols[n4] = n0 + wn * 64 + n4 * 16 + l15;
        bvv[n4]  = bias[cols[n4]];
    }
#pragma unroll
    for (int m4 = 0; m4 < 4; ++m4) {
        int rbase = m0 + wm * 64 + m4 * 16 + quad * 4;
#pragma unroll
        for (int n4 = 0; n4 < 4; ++n4) {
            float v[4];
#pragma unroll
            for (int rr = 0; rr < 4; ++rr)
                v[rr] = acc[m4][n4][rr] + bvv[n4];
            if (mode == 1) {
                int kvl = rbase & 2047;
                int pos = (kvl & ~31) + ((kvl >> 2) & 3) * 8 + ((kvl >> 4) & 1) * 4;
                size_t base = ((size_t)((rbase >> 11) * 1024 + cols[n4])) * 2048 + pos;
                uint2 o;
                o.x = pack_bf2(v[0], v[1]);
                o.y = pack_bf2(v[2], v[3]);
                *(uint2*)((ushort*)Cv + base) = o;
            } else {
#pragma unroll
                for (int rr = 0; rr < 4; ++rr)
                    ((float*)Cv)[(size_t)(rbase + rr) * 1024 + cols[n4]] = v[rr];
            }
        }
    }
}

// Fused Q/K/V projections, 768 blocks, 1 block/CU:
//   rounds 1-2: 512 full 256^2 tiles (Q:128, K:256, V-lower:128)
//   round 3   : 256 half-M 128x256 blocks (V-upper 128 tiles) on ALL CUs
__global__ __launch_bounds__(512, 2) void proj_qkv(
        const ushort* __restrict__ latB, const ushort* __restrict__ datB,
        const ushort* __restrict__ wqT, const ushort* __restrict__ wkT,
        const ushort* __restrict__ wvT,
        const float* __restrict__ bq, const float* __restrict__ bk,
        const float* __restrict__ bv,
        ushort* __restrict__ Qb, ushort* __restrict__ Kb, ushort* __restrict__ Vtb,
        float qscale) {
    __shared__ __align__(16) ushort sm[65536];   // 128 KiB
    int bx = blockIdx.x;
    if (bx < 512) {
        int bid = (bx & 7) * 64 + (bx >> 3);
        const ushort* A; const ushort* W; const float* bias;
        void* C; float sc; int mode, idx;
        if (bid < 128)      { A = latB; W = wqT; bias = bq; C = Qb;  sc = qscale; mode = 0; idx = bid; }
        else if (bid < 384) { A = datB; W = wkT; bias = bk; C = Kb;  sc = 1.f;    mode = 0; idx = bid - 128; }
        else                { A = datB; W = wvT; bias = bv; C = Vtb; sc = 1.f;    mode = 1; idx = bid - 384; }
        gemm256_body(A, W, bias, C, sm, sc, mode, idx >> 2, idx & 3);
    } else {
        int t  = bx - 512;
        int tt = (t & 7) * 32 + (t >> 3);
        int vtile = 128 + (tt >> 1);
        int mhalf = tt & 1;
        int m0 = (vtile >> 2) * 256 + mhalf * 128;
        int n0 = (vtile & 3) * 256;
        gemm128_body(datB, wvT, bv, Vtb, sm, m0, n0, 1);
    }
}

// O projection: 256 half-M tiles (128x256) = exactly one round on 256 CUs.
// Replaces the 128^2 gemm_bt (44us) with the proven half-tile body (~23us
// per 256-block round measured in R5's proj tail). 96 KiB LDS -> 1 block/CU.
__global__ __launch_bounds__(512, 1) void gemm_o(
        const ushort* __restrict__ AO, const ushort* __restrict__ woT,
        const float* __restrict__ bo, float* __restrict__ out) {
    __shared__ __align__(16) ushort sm[49152];   // 96 KiB
    int bx  = blockIdx.x;
    int bid = (bx & 7) * 32 + (bx >> 3);         // XCD-chunked (256 % 8 == 0)
    int m0  = (bid >> 2) * 128;
    int n0  = (bid & 3) * 256;
    gemm128_body(AO, woT, bo, out, sm, m0, n0, 2);
}

// ---------------------------------------------------------------------------
// Fused flash attention, S^T formulation, fixed-max base-2 softmax.
// R6: T3 2-phase kv double-buffer. Old loop staged serially each tile
// (barrier -> gld_lds -> vmcnt(0)-drain barrier -> compute): HBM/L2 stage
// latency sat on the critical path 16x. Now: stage tile t+1 into buf^1
// BEFORE computing tile t from buf; one vmcnt(0)+barrier per tile at the
// END, whose wait is covered by ~2000cy of compute. Hazard: iter-t ds_reads
// of buf complete before each wave's last consuming MFMA (lgkmcnt) -> before
// the end barrier -> overwriting buf in t+1 is safe. LDS 32->64 KiB,
// occupancy 4->2 blocks/CU (latency-hiding moves from TLP to ILP).
// ---------------------------------------------------------------------------
__global__ __launch_bounds__(256, 2) void attn_fused(const ushort* __restrict__ Q,
                                                     const ushort* __restrict__ K,
                                                     const ushort* __restrict__ Vt,
                                                     ushort* __restrict__ O) {
    __shared__ __align__(16) ushort smem[2 * 16384];   // 64 KiB: 2 x (K 16K + V 16K)

    const int tid  = threadIdx.x;
    const int wave = tid >> 6, lane = tid & 63;
    const int l15 = lane & 15, quad = lane >> 4;
    const int bx = blockIdx.x;
    // q-tile in HIGH bits: the 8 q-blocks of one (b,h) are == mod 8 in
    // dispatch order -> same XCD -> K/V tiles shared in that L2.
    const int bh = bx & 127, h = bh & 15, b = bh >> 4;
    const int q0 = (bx >> 7) * 128;

    const ushort* Qg = Q + ((size_t)(b * 1024 + q0)) * 1024 + h * 64;
    const ushort* Kg = K + ((size_t)(b * 2048)) * 1024 + h * 64;
    const ushort* Vg = Vt + ((size_t)(b * 1024 + h * 64)) * 2048;

    // --- Q fragments straight to registers (B-frag: n=q=l15, k=quad*8+j)
    short8 bq[2][2];
#pragma unroll
    for (int qt = 0; qt < 2; ++qt) {
        int row = wave * 32 + qt * 16 + l15;
#pragma unroll
        for (int ks = 0; ks < 2; ++ks)
            bq[ks][qt] = *(const short8*)(Qg + (size_t)row * 1024 + ks * 32 + quad * 8);
    }

    f32x4 Oacc[4][2] = {};
    float l_run[2] = {0.f, 0.f};

    const int rig = lane >> 3;        // K staging: row in 8-row group
    const int scb8 = (lane & 7) ^ rig;
    const int riv = lane >> 4;        // V staging: row in 4-row group
    const int cb16 = lane & 15;

#define STAGE_KV(KS, VS, KV)                                                      \
    _Pragma("unroll")                                                             \
    for (int g = 0; g < 4; ++g) {                                                 \
        int G = wave * 4 + g;                                                     \
        gld_lds16(Kg + (size_t)((KV) + G * 8 + rig) * 1024 + scb8 * 8, (KS) + G * 512); \
        int vrow = G * 4 + riv;                                                   \
        int scv = cb16 ^ (vrow & 15);                                             \
        gld_lds16(Vg + (size_t)vrow * 2048 + (KV) + scv * 8, (VS) + G * 512);     \
    }

    // prologue: tile 0 into buf 0
    STAGE_KV(smem, smem + 8192, 0)
    asm volatile("s_waitcnt vmcnt(0)" ::: "memory");
    __builtin_amdgcn_s_barrier();

    int cur = 0;
    for (int kv0 = 0; kv0 < 2048; kv0 += 128) {
        ushort* Ks  = smem + cur * 16384;
        ushort* Vts = Ks + 8192;
        // --- issue next tile's stage into the other buffer (overlaps compute)
        if (kv0 + 128 < 2048) {
            ushort* Ksn  = smem + (cur ^ 1) * 16384;
            STAGE_KV(Ksn, Ksn + 8192, kv0 + 128)
        }

        __builtin_amdgcn_s_setprio(1);
        // --- per kv-tile: S^T tile = K·Q^T, then exp2 + sum + pack at once
        unsigned pk[8][2][2];
#pragma unroll
        for (int kvt = 0; kvt < 8; ++kvt) {
            f32x4 s0 = {}, s1 = {};
#pragma unroll
            for (int ks = 0; ks < 2; ++ks) {
                int ck = ((ks * 4 + quad) ^ (l15 & 7)) * 8;   // swizzled chunk
                short8 ak = *(const short8*)(Ks + (kvt * 16 + l15) * 64 + ck);
                s0 = __builtin_amdgcn_mfma_f32_16x16x32_bf16(ak, bq[ks][0], s0, 0, 0, 0);
                s1 = __builtin_amdgcn_mfma_f32_16x16x32_bf16(ak, bq[ks][1], s1, 0, 0, 0);
            }
            float p0[4], p1[4];
#pragma unroll
            for (int rr = 0; rr < 4; ++rr) {
                p0[rr] = __builtin_amdgcn_exp2f(s0[rr]);
                p1[rr] = __builtin_amdgcn_exp2f(s1[rr]);
                l_run[0] += p0[rr];
                l_run[1] += p1[rr];
            }
            pk[kvt][0][0] = pack_bf2(p0[0], p0[1]);
            pk[kvt][0][1] = pack_bf2(p0[2], p0[3]);
            pk[kvt][1][0] = pack_bf2(p1[0], p1[1]);
            pk[kvt][1][1] = pack_bf2(p1[2], p1[3]);
        }

        // --- O^T += V^T · P^T : P^T B-frags straight from pk registers
#pragma unroll
        for (int sp = 0; sp < 4; ++sp) {
#pragma unroll
            for (int dt = 0; dt < 4; ++dt) {
                int cv = ((sp * 4 + quad) ^ l15) * 8;
                short8 av = *(const short8*)(Vts + (dt * 16 + l15) * 128 + cv);
#pragma unroll
                for (int qt = 0; qt < 2; ++qt) {
                    uint4v u = {pk[2 * sp][qt][0], pk[2 * sp][qt][1],
                                pk[2 * sp + 1][qt][0], pk[2 * sp + 1][qt][1]};
                    short8 bp = __builtin_bit_cast(short8, u);
                    Oacc[dt][qt] = __builtin_amdgcn_mfma_f32_16x16x32_bf16(av, bp, Oacc[dt][qt], 0, 0, 0);
                }
            }
        }
        __builtin_amdgcn_s_setprio(0);

        // --- next tile staged + this tile's reads done -> safe to swap
        asm volatile("s_waitcnt vmcnt(0)" ::: "memory");
        __builtin_amdgcn_s_barrier();
        cur ^= 1;
    }
#undef STAGE_KV

    // --- epilogue: reduce l across quads, O = (O^T)^T / l, packed 8B stores
#pragma unroll
    for (int qt = 0; qt < 2; ++qt) {
        float l = l_run[qt];
        l += __shfl_xor(l, 16);
        l += __shfl_xor(l, 32);
        float inv = 1.f / l;
        int qg = q0 + wave * 32 + qt * 16 + l15;
#pragma unroll
        for (int dt = 0; dt < 4; ++dt) {
            uint2 o;
            o.x = pack_bf2(Oacc[dt][qt][0] * inv, Oacc[dt][qt][1] * inv);
            o.y = pack_bf2(Oacc[dt][qt][2] * inv, Oacc[dt][qt][3] * inv);
            *(uint2*)(O + ((size_t)(b * 1024 + qg)) * 1024 + h * 64 + dt * 16 + quad * 4) = o;
        }
    }
}

// ---------------------------------------------------------------------------
extern "C" void kernel_launch(void* const* d_in, const int* in_sizes, int n_in,
                              void* d_out, int out_size, void* d_ws, size_t ws_size,
                              hipStream_t stream) {
    const float* latent = (const float*)d_in[0];
    const float* data   = (const float*)d_in[1];
    const float* wq     = (const float*)d_in[2];
    const float* bq     = (const float*)d_in[3];
    const float* wk     = (const float*)d_in[4];
    const float* bk     = (const float*)d_in[5];
    const float* wv     = (const float*)d_in[6];
    const float* bv     = (const float*)d_in[7];
    const float* wo     = (const float*)d_in[8];
    const float* bo     = (const float*)d_in[9];
    float* out = (float*)d_out;

    ushort* ws   = (ushort*)d_ws;
    ushort* wqT  = ws;
    ushort* wkT  = wqT + (1u << 20);
    ushort* wvT  = wkT + (1u << 20);
    ushort* woT  = wvT + (1u << 20);
    ushort* latB = woT + (1u << 20);
    ushort* datB = latB + (8u << 20);
    ushort* Qb   = datB + (16u << 20);
    ushort* Kb   = Qb + (8u << 20);
    ushort* Vtb  = Kb + (16u << 20);
    ushort* AO   = latB;               // alias: latB dead after proj_qkv
    // total ws footprint: 68M ushorts = 136 MB

    // fused prep: latent/data cvt + 4 weight transposes, one launch
    prep_fused<<<dim3(16384), 256, 0, stream>>>(latent, data, wq, wk, wv, wo,
                                                latB, datB, wqT, wkT, wvT, woT);

    const float qscale = 0.125f * 1.44269504088896340736f;  // HD^-0.5 * log2(e)
    // Q | K | V projections, 768 blocks (512 full + 256 tail-fill halves)
    proj_qkv<<<dim3(768), 512, 0, stream>>>(latB, datB, wqT, wkT, wvT,
                                            bq, bk, bv, Qb, Kb, Vtb, qscale);
    // fused attention -> AO [8192 x 1024] bf16
    attn_fused<<<dim3(1024), 256, 0, stream>>>(Qb, Kb, Vtb, AO);
    // out = AO @ wo + bo : 256 half-tiles, one full round
    gemm_o<<<dim3(256), 512, 0, stream>>>(AO, woT, bo, out);
}